// Round 6
// baseline (278.298 us; speedup 1.0000x reference)
//
#include <hip/hip_runtime.h>

#define SEQ 6
#define THREADS 256              // 4 waves; 10 elements per wave (60 active lanes)
#define ELB 40                   // elements per block
#define NL 2
#define VOC 15

typedef __attribute__((ext_vector_type(8))) _Float16 h8;
typedef __attribute__((ext_vector_type(2))) _Float16 h2;
typedef __attribute__((ext_vector_type(4))) float    f32x4;

// LDS: 2 pools x 256 slots x 16 u32, XOR-swizzled 16B groups. 8192 u32 = 32 KB.
// Slot = tid (wave w owns slots 64w..64w+63). All intra-layer traffic is
// within-wave (in-order DS pipe) -> zero barriers until logits staging.
#define XN 0          // Xn -> Q -> V -> OWo -> H -> FFN2
#define KP 4096       // K -> O -> Xn2 -> logits f32
#define SMEM_U32 8192

// ws layout (u32): per layer L at L*6144: Wq 0, Wk 512, Wv 1024, Wo 1536,
// quarter q: 2048+q*1024 (W1q at +0, W2q at +512). TE at 12288 (256).

__device__ __forceinline__ unsigned int pkh(float a, float b) {
    auto h = __builtin_amdgcn_cvt_pkrtz(a, b);
    return __builtin_bit_cast(unsigned int, h);
}
__device__ __forceinline__ float lo16(unsigned int u) {
    h2 h = __builtin_bit_cast(h2, u); return (float)h.x;
}
__device__ __forceinline__ float hi16(unsigned int u) {
    h2 h = __builtin_bit_cast(h2, u); return (float)h.y;
}
__device__ __forceinline__ h8 ldh(const unsigned int* p) {
    uint4 u = *(const uint4*)p;
    return __builtin_bit_cast(h8, u);
}
#if __has_builtin(__builtin_amdgcn_fdot2)
__device__ __forceinline__ float dot2acc(unsigned int a, unsigned int b, float c) {
    return __builtin_amdgcn_fdot2(__builtin_bit_cast(h2, a), __builtin_bit_cast(h2, b), c, false);
}
#else
__device__ __forceinline__ float dot2acc(unsigned int a, unsigned int b, float c) {
    return fmaf(hi16(a), hi16(b), fmaf(lo16(a), lo16(b), c));
}
#endif
__device__ __forceinline__ float gelu_f(float x) {   // sigmoid-form tanh-GELU
    float t = x * x;
    float v = x * fmaf(0.0713548162726f, t, 1.5957691216057308f);
    return x * __builtin_amdgcn_rcpf(1.0f + __expf(-v));
}
__device__ __forceinline__ int permc(int p) {        // head-local sigma pairs
    int h = (p & 15) >> 2, j = p & 3, hi = p >> 4;
    return 8*h + 2*j + hi;
}
__device__ __forceinline__ int swg(int row, int g) { // swizzled 16B-group offset
    return ((g ^ ((row >> 1) & 3)) << 2);
}
__device__ __forceinline__ void ln_write(const float* X, unsigned int* base, int row) {
    float mu = 0.f;
    #pragma unroll
    for (int c = 0; c < 32; ++c) mu += X[c];
    mu *= 0.03125f;
    float var = 0.f;
    #pragma unroll
    for (int c = 0; c < 32; ++c) { float d = X[c] - mu; var += d * d; }
    var *= 0.03125f;
    float rs = rsqrtf(var + 1e-5f), b = -mu * rs;
    unsigned int* rp = base + row * 16;
    const int k = (row >> 1) & 3;
    #pragma unroll
    for (int g = 0; g < 4; ++g) {
        uint4 w;
        w.x = pkh(fmaf(X[4*g+0], rs, b), fmaf(X[16+4*g+0], rs, b));
        w.y = pkh(fmaf(X[4*g+1], rs, b), fmaf(X[16+4*g+1], rs, b));
        w.z = pkh(fmaf(X[4*g+2], rs, b), fmaf(X[16+4*g+2], rs, b));
        w.w = pkh(fmaf(X[4*g+3], rs, b), fmaf(X[16+4*g+3], rs, b));
        *(uint4*)&rp[(g ^ k) << 2] = w;
    }
}

// ---- prep: pre-pack all weights (f16, transposed, head-permuted) into ws ----
__global__ __launch_bounds__(64) void prep(
    const float* __restrict__ temb, const float* __restrict__ wq,
    const float* __restrict__ wk, const float* __restrict__ wv,
    const float* __restrict__ wo, const float* __restrict__ w1,
    const float* __restrict__ w2, unsigned int* __restrict__ ws)
{
    const int part = blockIdx.x;          // 0..24
    const int t = threadIdx.x;
    if (part == 24) {                     // TE tile
        for (int i = t; i < 256; i += 64) {
            int c = i >> 4, w = i & 15;
            ws[12288 + i] = (c < VOC) ? pkh(temb[c*32 + w], temb[c*32 + w + 16]) : 0u;
        }
        return;
    }
    const int L = part / 12, m = part % 12;
    unsigned int* o = ws + L * 6144;
    for (int i = t; i < 512; i += 64) {
        int c = i >> 4, w = i & 15;
        if (m < 3) {
            const float* M = (m == 0 ? wq : (m == 1 ? wk : wv)) + L*1024;
            int pc = permc(c);
            o[m*512 + i] = pkh(M[w*32 + pc], M[(w+16)*32 + pc]);
        } else if (m == 3) {
            const float* M = wo + L*1024;
            o[1536 + i] = pkh(M[permc(w)*32 + c], M[permc(w+16)*32 + c]);
        } else if (m < 8) {
            int q = m - 4;
            const float* M = w1 + L*4096;
            o[2048 + q*1024 + i] = pkh(M[w*128 + 32*q + c], M[(w+16)*128 + 32*q + c]);
        } else {
            int q = m - 8;
            const float* M = w2 + L*4096;
            o[2048 + q*1024 + 512 + i] = pkh(M[(32*q+w)*32 + c], M[(32*q+16+w)*32 + c]);
        }
    }
}

__global__ __launch_bounds__(THREADS, 5)
void tf_mfma(const int* __restrict__ toks, const float* __restrict__ temb,
             const float* __restrict__ pemb, const unsigned int* __restrict__ ws,
             float* __restrict__ out, int nelem)
{
    __shared__ unsigned int S[SMEM_U32];
    const int tid  = threadIdx.x;
    const int lane = tid & 63;
    const int wid  = tid >> 6;
    const int llo  = lane & 15, lhi = lane >> 4;
    const int boff = 4 * lhi;
    int le = lane / 6;
    int s  = lane - le * 6;
    if (le > 9) { le = 9; s = 5; }                   // 4 dup lanes/wave (in-bounds)
    const int rb   = wid*64 + le*6;                  // element's slot base (in-wave)
    const int myk  = (tid >> 1) & 3;
    const int elem = blockIdx.x * ELB + wid*10 + le;
    const f32x4 zz = {0.f, 0.f, 0.f, 0.f};

    float X[32];
    {
        const int ti  = (elem < nelem) ? (elem*SEQ + s) : 0;
        const int tok = toks[ti];
        #pragma unroll
        for (int g = 0; g < 8; ++g) {
            float4 a = *(const float4*)&temb[tok*32 + 4*g];
            float4 b = *(const float4*)&pemb[s*32 + 4*g];
            X[4*g+0] = a.x + b.x; X[4*g+1] = a.y + b.y;
            X[4*g+2] = a.z + b.z; X[4*g+3] = a.w + b.w;
        }
    }

    #pragma unroll 1
    for (int L = 0; L < NL; ++L) {
        const unsigned int* wsL = ws + L * 6144;

        ln_write(X, &S[XN], tid);                    // Xn (own slot)

        // ---- QKV (weights direct from global; all LDS traffic in-wave) ----
        uint4 q4[4];
        {
            h8 bq0 = ldh(wsL +          llo    *16 + boff);
            h8 bq1 = ldh(wsL +         (llo+16)*16 + boff);
            h8 bk0 = ldh(wsL +  512 +   llo    *16 + boff);
            h8 bk1 = ldh(wsL +  512 +  (llo+16)*16 + boff);
            h8 bv0 = ldh(wsL + 1024 +   llo    *16 + boff);
            h8 bv1 = ldh(wsL + 1024 +  (llo+16)*16 + boff);
            h8 aa[4];
            #pragma unroll
            for (int j = 0; j < 4; ++j) {
                int rowa = wid*64 + j*16 + llo;
                aa[j] = ldh(&S[XN + rowa*16 + swg(rowa, lhi)]);
            }
            #pragma unroll
            for (int j = 0; j < 4; ++j) {            // K -> KP
                f32x4 k0 = __builtin_amdgcn_mfma_f32_16x16x32_f16(aa[j], bk0, zz, 0,0,0);
                f32x4 k1 = __builtin_amdgcn_mfma_f32_16x16x32_f16(aa[j], bk1, zz, 0,0,0);
                int rowb = wid*64 + j*16 + lhi*4;
                #pragma unroll
                for (int rg = 0; rg < 4; ++rg) {
                    int row = rowb + rg;
                    S[KP + row*16 + swg(row, llo >> 2) + (llo & 3)] = pkh(k0[rg], k1[rg]);
                }
            }
            #pragma unroll
            for (int j = 0; j < 4; ++j) {            // Q -> XN (over Xn; aa read done)
                f32x4 qa = __builtin_amdgcn_mfma_f32_16x16x32_f16(aa[j], bq0, zz, 0,0,0);
                f32x4 qb = __builtin_amdgcn_mfma_f32_16x16x32_f16(aa[j], bq1, zz, 0,0,0);
                int rowb = wid*64 + j*16 + lhi*4;
                #pragma unroll
                for (int rg = 0; rg < 4; ++rg) {
                    int row = rowb + rg;
                    S[XN + row*16 + swg(row, llo >> 2) + (llo & 3)] = pkh(qa[rg], qb[rg]);
                }
            }
            #pragma unroll
            for (int h = 0; h < 4; ++h)              // own-row Q (in-wave RAW, in-order DS)
                q4[h] = *(const uint4*)&S[XN + tid*16 + ((h ^ myk) << 2)];
            #pragma unroll
            for (int j = 0; j < 4; ++j) {            // V -> XN (over Q; q4 reads issued)
                f32x4 v0 = __builtin_amdgcn_mfma_f32_16x16x32_f16(aa[j], bv0, zz, 0,0,0);
                f32x4 v1 = __builtin_amdgcn_mfma_f32_16x16x32_f16(aa[j], bv1, zz, 0,0,0);
                int rowb = wid*64 + j*16 + lhi*4;
                #pragma unroll
                for (int rg = 0; rg < 4; ++rg) {
                    int row = rowb + rg;
                    S[XN + row*16 + swg(row, llo >> 2) + (llo & 3)] = pkh(v0[rg], v1[rg]);
                }
            }
        }

        // ---- scores + softmax (K rows in-wave) ----
        float p[4][SEQ], rd[4];
        {
            float den[4] = {0.f, 0.f, 0.f, 0.f};
            #pragma unroll
            for (int t = 0; t < SEQ; ++t) {
                int krow = rb + t;
                const unsigned int* kr = &S[KP + krow*16];
                int kk4 = (krow >> 1) & 3;
                float msk = (t <= s) ? 0.f : -1e30f;
                #pragma unroll
                for (int h = 0; h < 4; ++h) {
                    uint4 kk = *(const uint4*)&kr[(h ^ kk4) << 2];
                    float d = dot2acc(q4[h].x, kk.x, 0.f);
                    d = dot2acc(q4[h].y, kk.y, d);
                    d = dot2acc(q4[h].z, kk.z, d);
                    d = dot2acc(q4[h].w, kk.w, d);
                    float e = __expf(fmaf(d, 0.35355339059327373f, msk));
                    p[h][t] = e; den[h] += e;
                }
            }
            #pragma unroll
            for (int h = 0; h < 4; ++h) rd[h] = __builtin_amdgcn_rcpf(den[h]);
        }
        // ---- PV (V rows in-wave) -> O -> KP own row (over K; score reads issued) ----
        {
            h2 O[16];
            #pragma unroll
            for (int w = 0; w < 16; ++w) O[w] = __builtin_bit_cast(h2, 0u);
            #pragma unroll
            for (int t = 0; t < SEQ; ++t) {
                int vrow = rb + t;
                const unsigned int* vr = &S[XN + vrow*16];
                int vk4 = (vrow >> 1) & 3;
                #pragma unroll
                for (int h = 0; h < 4; ++h) {
                    float wg = p[h][t] * rd[h];
                    h2 wg2 = __builtin_bit_cast(h2, pkh(wg, wg));
                    uint4 vv = *(const uint4*)&vr[(h ^ vk4) << 2];
                    O[4*h+0] += __builtin_bit_cast(h2, vv.x) * wg2;
                    O[4*h+1] += __builtin_bit_cast(h2, vv.y) * wg2;
                    O[4*h+2] += __builtin_bit_cast(h2, vv.z) * wg2;
                    O[4*h+3] += __builtin_bit_cast(h2, vv.w) * wg2;
                }
            }
            #pragma unroll
            for (int g = 0; g < 4; ++g) {
                uint4 w;
                w.x = __builtin_bit_cast(unsigned int, O[4*g+0]);
                w.y = __builtin_bit_cast(unsigned int, O[4*g+1]);
                w.z = __builtin_bit_cast(unsigned int, O[4*g+2]);
                w.w = __builtin_bit_cast(unsigned int, O[4*g+3]);
                *(uint4*)&S[KP + tid*16 + ((g ^ myk) << 2)] = w;
            }
        }

        // ---- O.Wo: A=KP(O) -> D=XN (over V; PV reads issued) ----
        {
            h8 bo0 = ldh(wsL + 1536 +  llo    *16 + boff);
            h8 bo1 = ldh(wsL + 1536 + (llo+16)*16 + boff);
            #pragma unroll
            for (int j = 0; j < 4; ++j) {
                int rowa = wid*64 + j*16 + llo;
                h8 a = ldh(&S[KP + rowa*16 + swg(rowa, lhi)]);
                f32x4 o0 = __builtin_amdgcn_mfma_f32_16x16x32_f16(a, bo0, zz, 0,0,0);
                f32x4 o1 = __builtin_amdgcn_mfma_f32_16x16x32_f16(a, bo1, zz, 0,0,0);
                int rowb = wid*64 + j*16 + lhi*4;
                #pragma unroll
                for (int rg = 0; rg < 4; ++rg) {
                    int row = rowb + rg;
                    S[XN + row*16 + swg(row, llo >> 2) + (llo & 3)] = pkh(o0[rg], o1[rg]);
                }
            }
        }
        #pragma unroll
        for (int g = 0; g < 4; ++g) {                // residual (own slot)
            uint4 v = *(const uint4*)&S[XN + tid*16 + ((g ^ myk) << 2)];
            X[4*g+0] += lo16(v.x); X[16+4*g+0] += hi16(v.x);
            X[4*g+1] += lo16(v.y); X[16+4*g+1] += hi16(v.y);
            X[4*g+2] += lo16(v.z); X[16+4*g+2] += hi16(v.z);
            X[4*g+3] += lo16(v.w); X[16+4*g+3] += hi16(v.w);
        }
        ln_write(X, &S[KP], tid);                    // Xn2 -> KP (over O; A reads issued)

        // ---- FFN: A=KP(Xn2), H->XN, FFN2 accumulates in regs ----
        f32x4 cf[4][2];
        #pragma unroll
        for (int j = 0; j < 4; ++j) { cf[j][0] = zz; cf[j][1] = zz; }
        #pragma unroll
        for (int q = 0; q < 4; ++q) {
            const unsigned int* wq4 = wsL + 2048 + q*1024;
            h8 b10 = ldh(wq4 +        llo    *16 + boff);
            h8 b11 = ldh(wq4 +       (llo+16)*16 + boff);
            h8 b20 = ldh(wq4 + 512 +  llo    *16 + boff);
            h8 b21 = ldh(wq4 + 512 + (llo+16)*16 + boff);
            #pragma unroll
            for (int j = 0; j < 4; ++j) {
                int rowa = wid*64 + j*16 + llo;
                h8 a = ldh(&S[KP + rowa*16 + swg(rowa, lhi)]);
                f32x4 h0 = __builtin_amdgcn_mfma_f32_16x16x32_f16(a, b10, zz, 0,0,0);
                f32x4 h1 = __builtin_amdgcn_mfma_f32_16x16x32_f16(a, b11, zz, 0,0,0);
                int rowb = wid*64 + j*16 + lhi*4;
                #pragma unroll
                for (int rg = 0; rg < 4; ++rg) {
                    int row = rowb + rg;
                    S[XN + row*16 + swg(row, llo >> 2) + (llo & 3)] =
                        pkh(gelu_f(h0[rg]), gelu_f(h1[rg]));
                }
            }
            #pragma unroll
            for (int j = 0; j < 4; ++j) {            // FFN2 (H rows in-wave)
                int rowa = wid*64 + j*16 + llo;
                h8 ah = ldh(&S[XN + rowa*16 + swg(rowa, lhi)]);
                cf[j][0] = __builtin_amdgcn_mfma_f32_16x16x32_f16(ah, b20, cf[j][0], 0,0,0);
                cf[j][1] = __builtin_amdgcn_mfma_f32_16x16x32_f16(ah, b21, cf[j][1], 0,0,0);
            }
        }
        #pragma unroll
        for (int j = 0; j < 4; ++j) {                // FFN2 out -> XN (over H)
            int rowb = wid*64 + j*16 + lhi*4;
            #pragma unroll
            for (int rg = 0; rg < 4; ++rg) {
                int row = rowb + rg;
                S[XN + row*16 + swg(row, llo >> 2) + (llo & 3)] = pkh(cf[j][0][rg], cf[j][1][rg]);
            }
        }
        #pragma unroll
        for (int g = 0; g < 4; ++g) {                // residual (own slot)
            uint4 v = *(const uint4*)&S[XN + tid*16 + ((g ^ myk) << 2)];
            X[4*g+0] += lo16(v.x); X[16+4*g+0] += hi16(v.x);
            X[4*g+1] += lo16(v.y); X[16+4*g+1] += hi16(v.y);
            X[4*g+2] += lo16(v.z); X[16+4*g+2] += hi16(v.z);
            X[4*g+3] += lo16(v.w); X[16+4*g+3] += hi16(v.w);
        }
    }

    // ---- final LN + weight-tied logits ----
    ln_write(X, &S[XN], tid);
    {
        h8 bt = ldh(ws + 12288 + llo*16 + boff);
        #pragma unroll
        for (int j = 0; j < 4; ++j) {
            int rowa = wid*64 + j*16 + llo;
            h8 a = ldh(&S[XN + rowa*16 + swg(rowa, lhi)]);
            f32x4 lg = __builtin_amdgcn_mfma_f32_16x16x32_f16(a, bt, zz, 0,0,0);
            int rowb = wid*64 + j*16 + lhi*4;
            #pragma unroll
            for (int rg = 0; rg < 4; ++rg) {
                int row = rowb + rg;
                S[KP + row*16 + swg(row, llo >> 2) + (llo & 3)] = __float_as_uint(lg[rg]);
            }
        }
    }
    __syncthreads();                                 // the only barrier
    {
        const long long obase = (long long)blockIdx.x * (ELB*SEQ*VOC);   // 3600
        const long long tot   = (long long)nelem * (SEQ*VOC);
        for (int i = tid; i < ELB*SEQ*VOC; i += THREADS) {
            if (obase + i < tot) {
                int rl   = i / VOC, col = i - rl*VOC;
                int w    = rl / 60, r6 = rl - w*60;
                int slot = w*64 + r6;
                out[obase + i] = __uint_as_float(
                    S[KP + slot*16 + (((col >> 2) ^ ((slot >> 1) & 3)) << 2) + (col & 3)]);
            }
        }
    }
}

extern "C" void kernel_launch(void* const* d_in, const int* in_sizes, int n_in,
                              void* d_out, int out_size, void* d_ws, size_t ws_size,
                              hipStream_t stream) {
    const int*   toks = (const int*)  d_in[0];
    const float* temb = (const float*)d_in[1];
    const float* pemb = (const float*)d_in[2];
    const float* wq   = (const float*)d_in[3];
    const float* wk   = (const float*)d_in[4];
    const float* wv   = (const float*)d_in[5];
    const float* wo   = (const float*)d_in[6];
    const float* w1   = (const float*)d_in[7];
    const float* w2   = (const float*)d_in[8];
    unsigned int* ws  = (unsigned int*)d_ws;         // 12544 u32 = 50 KB used
    float* out = (float*)d_out;
    const int nelem = in_sizes[0] / SEQ;             // 131072
    const int nblk  = (nelem + ELB - 1) / ELB;       // 3277

    prep<<<dim3(25), dim3(64), 0, stream>>>(temb, wq, wk, wv, wo, w1, w2, ws);
    tf_mfma<<<dim3(nblk), dim3(THREADS), 0, stream>>>(toks, temb, pemb, ws, out, nelem);
}

// Round 7
// 183.729 us; speedup vs baseline: 1.5147x; 1.5147x over previous
//
#include <hip/hip_runtime.h>

#define SEQ 6
#define THREADS 256              // 4 waves; 10 elements per wave (60 active lanes)
#define ELB 40                   // elements per block
#define NL 2
#define VOC 15

typedef __attribute__((ext_vector_type(8))) _Float16 h8;
typedef __attribute__((ext_vector_type(2))) _Float16 h2;
typedef __attribute__((ext_vector_type(4))) float    f32x4;

// LDS: 2 pools x 256 slots x 16 u32, XOR-swizzled 16B groups. 8192 u32 = 32 KB.
// Slot = tid (wave w owns slots 64w..64w+63). All intra-layer traffic is
// within-wave (in-order DS pipe) -> zero barriers until logits staging.
#define XN 0          // Xn -> Q -> V -> OWo -> H -> FFN2
#define KP 4096       // K -> O -> Xn2 -> logits f32
#define SMEM_U32 8192

// ws layout (u32): per layer L at L*6144: Wq 0, Wk 512, Wv 1024, Wo 1536,
// quarter q: 2048+q*1024 (W1q at +0, W2q at +512). TE at 12288 (256).

__device__ __forceinline__ unsigned int pkh(float a, float b) {
    auto h = __builtin_amdgcn_cvt_pkrtz(a, b);
    return __builtin_bit_cast(unsigned int, h);
}
__device__ __forceinline__ float lo16(unsigned int u) {
    h2 h = __builtin_bit_cast(h2, u); return (float)h.x;
}
__device__ __forceinline__ float hi16(unsigned int u) {
    h2 h = __builtin_bit_cast(h2, u); return (float)h.y;
}
__device__ __forceinline__ h8 ldh(const unsigned int* p) {
    uint4 u = *(const uint4*)p;
    return __builtin_bit_cast(h8, u);
}
#if __has_builtin(__builtin_amdgcn_fdot2)
__device__ __forceinline__ float dot2acc(unsigned int a, unsigned int b, float c) {
    return __builtin_amdgcn_fdot2(__builtin_bit_cast(h2, a), __builtin_bit_cast(h2, b), c, false);
}
#else
__device__ __forceinline__ float dot2acc(unsigned int a, unsigned int b, float c) {
    return fmaf(hi16(a), hi16(b), fmaf(lo16(a), lo16(b), c));
}
#endif
__device__ __forceinline__ float gelu_f(float x) {   // sigmoid-form tanh-GELU
    float t = x * x;
    float v = x * fmaf(0.0713548162726f, t, 1.5957691216057308f);
    return x * __builtin_amdgcn_rcpf(1.0f + __expf(-v));
}
__device__ __forceinline__ int permc(int p) {        // head-local sigma pairs
    int h = (p & 15) >> 2, j = p & 3, hi = p >> 4;
    return 8*h + 2*j + hi;
}
__device__ __forceinline__ int swg(int row, int g) { // swizzled 16B-group offset
    return ((g ^ ((row >> 1) & 3)) << 2);
}
__device__ __forceinline__ void ln_write(const float* X, unsigned int* base, int row) {
    float mu = 0.f;
    #pragma unroll
    for (int c = 0; c < 32; ++c) mu += X[c];
    mu *= 0.03125f;
    float var = 0.f;
    #pragma unroll
    for (int c = 0; c < 32; ++c) { float d = X[c] - mu; var += d * d; }
    var *= 0.03125f;
    float rs = rsqrtf(var + 1e-5f), b = -mu * rs;
    unsigned int* rp = base + row * 16;
    const int k = (row >> 1) & 3;
    #pragma unroll
    for (int g = 0; g < 4; ++g) {
        uint4 w;
        w.x = pkh(fmaf(X[4*g+0], rs, b), fmaf(X[16+4*g+0], rs, b));
        w.y = pkh(fmaf(X[4*g+1], rs, b), fmaf(X[16+4*g+1], rs, b));
        w.z = pkh(fmaf(X[4*g+2], rs, b), fmaf(X[16+4*g+2], rs, b));
        w.w = pkh(fmaf(X[4*g+3], rs, b), fmaf(X[16+4*g+3], rs, b));
        *(uint4*)&rp[(g ^ k) << 2] = w;
    }
}

// ---- prep: pre-pack all weights (f16, transposed, head-permuted) into ws ----
__global__ __launch_bounds__(64) void prep(
    const float* __restrict__ temb, const float* __restrict__ wq,
    const float* __restrict__ wk, const float* __restrict__ wv,
    const float* __restrict__ wo, const float* __restrict__ w1,
    const float* __restrict__ w2, unsigned int* __restrict__ ws)
{
    const int part = blockIdx.x;          // 0..24
    const int t = threadIdx.x;
    if (part == 24) {                     // TE tile
        for (int i = t; i < 256; i += 64) {
            int c = i >> 4, w = i & 15;
            ws[12288 + i] = (c < VOC) ? pkh(temb[c*32 + w], temb[c*32 + w + 16]) : 0u;
        }
        return;
    }
    const int L = part / 12, m = part % 12;
    unsigned int* o = ws + L * 6144;
    for (int i = t; i < 512; i += 64) {
        int c = i >> 4, w = i & 15;
        if (m < 3) {
            const float* M = (m == 0 ? wq : (m == 1 ? wk : wv)) + L*1024;
            int pc = permc(c);
            o[m*512 + i] = pkh(M[w*32 + pc], M[(w+16)*32 + pc]);
        } else if (m == 3) {
            const float* M = wo + L*1024;
            o[1536 + i] = pkh(M[permc(w)*32 + c], M[permc(w+16)*32 + c]);
        } else if (m < 8) {
            int q = m - 4;
            const float* M = w1 + L*4096;
            o[2048 + q*1024 + i] = pkh(M[w*128 + 32*q + c], M[(w+16)*128 + 32*q + c]);
        } else {
            int q = m - 8;
            const float* M = w2 + L*4096;
            o[2048 + q*1024 + 512 + i] = pkh(M[(32*q+w)*32 + c], M[(32*q+16+w)*32 + c]);
        }
    }
}

__global__ __launch_bounds__(THREADS, 4)   // VGPR cap 128: no spills (R6's ,5 => 48 VGPR + 1GB scratch)
void tf_mfma(const int* __restrict__ toks, const float* __restrict__ temb,
             const float* __restrict__ pemb, const unsigned int* __restrict__ ws,
             float* __restrict__ out, int nelem)
{
    __shared__ unsigned int S[SMEM_U32];
    const int tid  = threadIdx.x;
    const int lane = tid & 63;
    const int wid  = tid >> 6;
    const int llo  = lane & 15, lhi = lane >> 4;
    const int boff = 4 * lhi;
    int le = lane / 6;
    int s  = lane - le * 6;
    if (le > 9) { le = 9; s = 5; }                   // 4 dup lanes/wave (in-bounds)
    const int rb   = wid*64 + le*6;                  // element's slot base (in-wave)
    const int myk  = (tid >> 1) & 3;
    const int elem = blockIdx.x * ELB + wid*10 + le;
    const f32x4 zz = {0.f, 0.f, 0.f, 0.f};

    float X[32];
    {
        const int ti  = (elem < nelem) ? (elem*SEQ + s) : 0;
        const int tok = toks[ti];
        #pragma unroll
        for (int g = 0; g < 8; ++g) {
            float4 a = *(const float4*)&temb[tok*32 + 4*g];
            float4 b = *(const float4*)&pemb[s*32 + 4*g];
            X[4*g+0] = a.x + b.x; X[4*g+1] = a.y + b.y;
            X[4*g+2] = a.z + b.z; X[4*g+3] = a.w + b.w;
        }
    }

    #pragma unroll 1
    for (int L = 0; L < NL; ++L) {
        const unsigned int* wsL = ws + L * 6144;

        ln_write(X, &S[XN], tid);                    // Xn (own slot)

        // ---- QKV (weights direct from global; all LDS traffic in-wave) ----
        uint4 q4[4];
        {
            h8 bq0 = ldh(wsL +          llo    *16 + boff);
            h8 bq1 = ldh(wsL +         (llo+16)*16 + boff);
            h8 bk0 = ldh(wsL +  512 +   llo    *16 + boff);
            h8 bk1 = ldh(wsL +  512 +  (llo+16)*16 + boff);
            h8 bv0 = ldh(wsL + 1024 +   llo    *16 + boff);
            h8 bv1 = ldh(wsL + 1024 +  (llo+16)*16 + boff);
            h8 aa[4];
            #pragma unroll
            for (int j = 0; j < 4; ++j) {
                int rowa = wid*64 + j*16 + llo;
                aa[j] = ldh(&S[XN + rowa*16 + swg(rowa, lhi)]);
            }
            #pragma unroll
            for (int j = 0; j < 4; ++j) {            // K -> KP
                f32x4 k0 = __builtin_amdgcn_mfma_f32_16x16x32_f16(aa[j], bk0, zz, 0,0,0);
                f32x4 k1 = __builtin_amdgcn_mfma_f32_16x16x32_f16(aa[j], bk1, zz, 0,0,0);
                int rowb = wid*64 + j*16 + lhi*4;
                #pragma unroll
                for (int rg = 0; rg < 4; ++rg) {
                    int row = rowb + rg;
                    S[KP + row*16 + swg(row, llo >> 2) + (llo & 3)] = pkh(k0[rg], k1[rg]);
                }
            }
            #pragma unroll
            for (int j = 0; j < 4; ++j) {            // Q -> XN (over Xn; aa read done)
                f32x4 qa = __builtin_amdgcn_mfma_f32_16x16x32_f16(aa[j], bq0, zz, 0,0,0);
                f32x4 qb = __builtin_amdgcn_mfma_f32_16x16x32_f16(aa[j], bq1, zz, 0,0,0);
                int rowb = wid*64 + j*16 + lhi*4;
                #pragma unroll
                for (int rg = 0; rg < 4; ++rg) {
                    int row = rowb + rg;
                    S[XN + row*16 + swg(row, llo >> 2) + (llo & 3)] = pkh(qa[rg], qb[rg]);
                }
            }
            #pragma unroll
            for (int h = 0; h < 4; ++h)              // own-row Q (in-wave RAW, in-order DS)
                q4[h] = *(const uint4*)&S[XN + tid*16 + ((h ^ myk) << 2)];
            #pragma unroll
            for (int j = 0; j < 4; ++j) {            // V -> XN (over Q; q4 reads issued)
                f32x4 v0 = __builtin_amdgcn_mfma_f32_16x16x32_f16(aa[j], bv0, zz, 0,0,0);
                f32x4 v1 = __builtin_amdgcn_mfma_f32_16x16x32_f16(aa[j], bv1, zz, 0,0,0);
                int rowb = wid*64 + j*16 + lhi*4;
                #pragma unroll
                for (int rg = 0; rg < 4; ++rg) {
                    int row = rowb + rg;
                    S[XN + row*16 + swg(row, llo >> 2) + (llo & 3)] = pkh(v0[rg], v1[rg]);
                }
            }
        }

        // ---- scores + softmax (K rows in-wave) ----
        float p[4][SEQ], rd[4];
        {
            float den[4] = {0.f, 0.f, 0.f, 0.f};
            #pragma unroll
            for (int t = 0; t < SEQ; ++t) {
                int krow = rb + t;
                const unsigned int* kr = &S[KP + krow*16];
                int kk4 = (krow >> 1) & 3;
                float msk = (t <= s) ? 0.f : -1e30f;
                #pragma unroll
                for (int h = 0; h < 4; ++h) {
                    uint4 kk = *(const uint4*)&kr[(h ^ kk4) << 2];
                    float d = dot2acc(q4[h].x, kk.x, 0.f);
                    d = dot2acc(q4[h].y, kk.y, d);
                    d = dot2acc(q4[h].z, kk.z, d);
                    d = dot2acc(q4[h].w, kk.w, d);
                    float e = __expf(fmaf(d, 0.35355339059327373f, msk));
                    p[h][t] = e; den[h] += e;
                }
            }
            #pragma unroll
            for (int h = 0; h < 4; ++h) rd[h] = __builtin_amdgcn_rcpf(den[h]);
        }
        // ---- PV (V rows in-wave) -> O -> KP own row (over K; score reads issued) ----
        {
            h2 O[16];
            #pragma unroll
            for (int w = 0; w < 16; ++w) O[w] = __builtin_bit_cast(h2, 0u);
            #pragma unroll
            for (int t = 0; t < SEQ; ++t) {
                int vrow = rb + t;
                const unsigned int* vr = &S[XN + vrow*16];
                int vk4 = (vrow >> 1) & 3;
                #pragma unroll
                for (int h = 0; h < 4; ++h) {
                    float wg = p[h][t] * rd[h];
                    h2 wg2 = __builtin_bit_cast(h2, pkh(wg, wg));
                    uint4 vv = *(const uint4*)&vr[(h ^ vk4) << 2];
                    O[4*h+0] += __builtin_bit_cast(h2, vv.x) * wg2;
                    O[4*h+1] += __builtin_bit_cast(h2, vv.y) * wg2;
                    O[4*h+2] += __builtin_bit_cast(h2, vv.z) * wg2;
                    O[4*h+3] += __builtin_bit_cast(h2, vv.w) * wg2;
                }
            }
            #pragma unroll
            for (int g = 0; g < 4; ++g) {
                uint4 w;
                w.x = __builtin_bit_cast(unsigned int, O[4*g+0]);
                w.y = __builtin_bit_cast(unsigned int, O[4*g+1]);
                w.z = __builtin_bit_cast(unsigned int, O[4*g+2]);
                w.w = __builtin_bit_cast(unsigned int, O[4*g+3]);
                *(uint4*)&S[KP + tid*16 + ((g ^ myk) << 2)] = w;
            }
        }

        // ---- O.Wo: A=KP(O) -> D=XN (over V; PV reads issued) ----
        {
            h8 bo0 = ldh(wsL + 1536 +  llo    *16 + boff);
            h8 bo1 = ldh(wsL + 1536 + (llo+16)*16 + boff);
            #pragma unroll
            for (int j = 0; j < 4; ++j) {
                int rowa = wid*64 + j*16 + llo;
                h8 a = ldh(&S[KP + rowa*16 + swg(rowa, lhi)]);
                f32x4 o0 = __builtin_amdgcn_mfma_f32_16x16x32_f16(a, bo0, zz, 0,0,0);
                f32x4 o1 = __builtin_amdgcn_mfma_f32_16x16x32_f16(a, bo1, zz, 0,0,0);
                int rowb = wid*64 + j*16 + lhi*4;
                #pragma unroll
                for (int rg = 0; rg < 4; ++rg) {
                    int row = rowb + rg;
                    S[XN + row*16 + swg(row, llo >> 2) + (llo & 3)] = pkh(o0[rg], o1[rg]);
                }
            }
        }
        #pragma unroll
        for (int g = 0; g < 4; ++g) {                // residual (own slot)
            uint4 v = *(const uint4*)&S[XN + tid*16 + ((g ^ myk) << 2)];
            X[4*g+0] += lo16(v.x); X[16+4*g+0] += hi16(v.x);
            X[4*g+1] += lo16(v.y); X[16+4*g+1] += hi16(v.y);
            X[4*g+2] += lo16(v.z); X[16+4*g+2] += hi16(v.z);
            X[4*g+3] += lo16(v.w); X[16+4*g+3] += hi16(v.w);
        }
        ln_write(X, &S[KP], tid);                    // Xn2 -> KP (over O; A reads issued)

        // ---- FFN: A=KP(Xn2), H->XN, FFN2 accumulates in regs ----
        f32x4 cf[4][2];
        #pragma unroll
        for (int j = 0; j < 4; ++j) { cf[j][0] = zz; cf[j][1] = zz; }
        #pragma unroll
        for (int q = 0; q < 4; ++q) {
            const unsigned int* wq4 = wsL + 2048 + q*1024;
            h8 b10 = ldh(wq4 +        llo    *16 + boff);
            h8 b11 = ldh(wq4 +       (llo+16)*16 + boff);
            h8 b20 = ldh(wq4 + 512 +  llo    *16 + boff);
            h8 b21 = ldh(wq4 + 512 + (llo+16)*16 + boff);
            #pragma unroll
            for (int j = 0; j < 4; ++j) {
                int rowa = wid*64 + j*16 + llo;
                h8 a = ldh(&S[KP + rowa*16 + swg(rowa, lhi)]);
                f32x4 h0 = __builtin_amdgcn_mfma_f32_16x16x32_f16(a, b10, zz, 0,0,0);
                f32x4 h1 = __builtin_amdgcn_mfma_f32_16x16x32_f16(a, b11, zz, 0,0,0);
                int rowb = wid*64 + j*16 + lhi*4;
                #pragma unroll
                for (int rg = 0; rg < 4; ++rg) {
                    int row = rowb + rg;
                    S[XN + row*16 + swg(row, llo >> 2) + (llo & 3)] =
                        pkh(gelu_f(h0[rg]), gelu_f(h1[rg]));
                }
            }
            #pragma unroll
            for (int j = 0; j < 4; ++j) {            // FFN2 (H rows in-wave)
                int rowa = wid*64 + j*16 + llo;
                h8 ah = ldh(&S[XN + rowa*16 + swg(rowa, lhi)]);
                cf[j][0] = __builtin_amdgcn_mfma_f32_16x16x32_f16(ah, b20, cf[j][0], 0,0,0);
                cf[j][1] = __builtin_amdgcn_mfma_f32_16x16x32_f16(ah, b21, cf[j][1], 0,0,0);
            }
        }
        #pragma unroll
        for (int j = 0; j < 4; ++j) {                // FFN2 out -> XN (over H)
            int rowb = wid*64 + j*16 + lhi*4;
            #pragma unroll
            for (int rg = 0; rg < 4; ++rg) {
                int row = rowb + rg;
                S[XN + row*16 + swg(row, llo >> 2) + (llo & 3)] = pkh(cf[j][0][rg], cf[j][1][rg]);
            }
        }
        #pragma unroll
        for (int g = 0; g < 4; ++g) {                // residual (own slot)
            uint4 v = *(const uint4*)&S[XN + tid*16 + ((g ^ myk) << 2)];
            X[4*g+0] += lo16(v.x); X[16+4*g+0] += hi16(v.x);
            X[4*g+1] += lo16(v.y); X[16+4*g+1] += hi16(v.y);
            X[4*g+2] += lo16(v.z); X[16+4*g+2] += hi16(v.z);
            X[4*g+3] += lo16(v.w); X[16+4*g+3] += hi16(v.w);
        }
    }

    // ---- final LN + weight-tied logits ----
    ln_write(X, &S[XN], tid);
    {
        h8 bt = ldh(ws + 12288 + llo*16 + boff);
        #pragma unroll
        for (int j = 0; j < 4; ++j) {
            int rowa = wid*64 + j*16 + llo;
            h8 a = ldh(&S[XN + rowa*16 + swg(rowa, lhi)]);
            f32x4 lg = __builtin_amdgcn_mfma_f32_16x16x32_f16(a, bt, zz, 0,0,0);
            int rowb = wid*64 + j*16 + lhi*4;
            #pragma unroll
            for (int rg = 0; rg < 4; ++rg) {
                int row = rowb + rg;
                S[KP + row*16 + swg(row, llo >> 2) + (llo & 3)] = __float_as_uint(lg[rg]);
            }
        }
    }
    __syncthreads();                                 // the only barrier
    {
        const long long obase = (long long)blockIdx.x * (ELB*SEQ*VOC);   // 3600
        const long long tot   = (long long)nelem * (SEQ*VOC);
        for (int i = tid; i < ELB*SEQ*VOC; i += THREADS) {
            if (obase + i < tot) {
                int rl   = i / VOC, col = i - rl*VOC;
                int w    = rl / 60, r6 = rl - w*60;
                int slot = w*64 + r6;
                out[obase + i] = __uint_as_float(
                    S[KP + slot*16 + (((col >> 2) ^ ((slot >> 1) & 3)) << 2) + (col & 3)]);
            }
        }
    }
}

extern "C" void kernel_launch(void* const* d_in, const int* in_sizes, int n_in,
                              void* d_out, int out_size, void* d_ws, size_t ws_size,
                              hipStream_t stream) {
    const int*   toks = (const int*)  d_in[0];
    const float* temb = (const float*)d_in[1];
    const float* pemb = (const float*)d_in[2];
    const float* wq   = (const float*)d_in[3];
    const float* wk   = (const float*)d_in[4];
    const float* wv   = (const float*)d_in[5];
    const float* wo   = (const float*)d_in[6];
    const float* w1   = (const float*)d_in[7];
    const float* w2   = (const float*)d_in[8];
    unsigned int* ws  = (unsigned int*)d_ws;         // 12544 u32 = 50 KB used
    float* out = (float*)d_out;
    const int nelem = in_sizes[0] / SEQ;             // 131072
    const int nblk  = (nelem + ELB - 1) / ELB;       // 3277

    prep<<<dim3(25), dim3(64), 0, stream>>>(temb, wq, wk, wv, wo, w1, w2, ws);
    tf_mfma<<<dim3(nblk), dim3(THREADS), 0, stream>>>(toks, temb, pemb, ws, out, nelem);
}

// Round 8
// 155.470 us; speedup vs baseline: 1.7900x; 1.1818x over previous
//
#include <hip/hip_runtime.h>

#define SEQ 6
#define THREADS 256              // 4 waves; 10 elements per wave (60 active lanes)
#define ELB 40                   // elements per block
#define NL 2
#define VOC 15

typedef __attribute__((ext_vector_type(8))) _Float16 h8;
typedef __attribute__((ext_vector_type(2))) _Float16 h2;
typedef __attribute__((ext_vector_type(4))) float    f32x4;

// LDS: 2 pools x 256 slots x 16 u32, XOR-swizzled 16B groups. 8192 u32 = 32 KB.
// Slot = tid (wave w owns slots 64w..64w+63). All intra-layer traffic is
// within-wave (in-order DS pipe) -> zero barriers until logits staging.
#define XN 0          // Xn -> Q -> V -> OWo -> H -> FFN2
#define KP 4096       // K -> O -> Xn2 -> logits f32
#define SMEM_U32 8192

// ws layout (u32): per layer L at L*6144: Wq 0, Wk 512, Wv 1024, Wo 1536,
// quarter q: 2048+q*1024 (W1q at +0, W2q at +512). TE at 12288 (256).

__device__ __forceinline__ unsigned int pkh(float a, float b) {
    auto h = __builtin_amdgcn_cvt_pkrtz(a, b);
    return __builtin_bit_cast(unsigned int, h);
}
__device__ __forceinline__ float lo16(unsigned int u) {
    h2 h = __builtin_bit_cast(h2, u); return (float)h.x;
}
__device__ __forceinline__ float hi16(unsigned int u) {
    h2 h = __builtin_bit_cast(h2, u); return (float)h.y;
}
__device__ __forceinline__ h8 ldh(const unsigned int* p) {
    uint4 u = *(const uint4*)p;
    return __builtin_bit_cast(h8, u);
}
#if __has_builtin(__builtin_amdgcn_fdot2)
__device__ __forceinline__ float dot2acc(unsigned int a, unsigned int b, float c) {
    return __builtin_amdgcn_fdot2(__builtin_bit_cast(h2, a), __builtin_bit_cast(h2, b), c, false);
}
#else
__device__ __forceinline__ float dot2acc(unsigned int a, unsigned int b, float c) {
    return fmaf(hi16(a), hi16(b), fmaf(lo16(a), lo16(b), c));
}
#endif
__device__ __forceinline__ float gelu_f(float x) {   // sigmoid-form tanh-GELU
    float t = x * x;
    float v = x * fmaf(0.0713548162726f, t, 1.5957691216057308f);
    return x * __builtin_amdgcn_rcpf(1.0f + __expf(-v));
}
__device__ __forceinline__ int permc(int p) {        // head-local sigma pairs
    int h = (p & 15) >> 2, j = p & 3, hi = p >> 4;
    return 8*h + 2*j + hi;
}
__device__ __forceinline__ int swg(int row, int g) { // swizzled 16B-group offset
    return ((g ^ ((row >> 1) & 3)) << 2);
}
__device__ __forceinline__ void ln_write(const float* X, unsigned int* base, int row) {
    float mu = 0.f;
    #pragma unroll
    for (int c = 0; c < 32; ++c) mu += X[c];
    mu *= 0.03125f;
    float var = 0.f;
    #pragma unroll
    for (int c = 0; c < 32; ++c) { float d = X[c] - mu; var += d * d; }
    var *= 0.03125f;
    float rs = rsqrtf(var + 1e-5f), b = -mu * rs;
    unsigned int* rp = base + row * 16;
    const int k = (row >> 1) & 3;
    #pragma unroll
    for (int g = 0; g < 4; ++g) {
        uint4 w;
        w.x = pkh(fmaf(X[4*g+0], rs, b), fmaf(X[16+4*g+0], rs, b));
        w.y = pkh(fmaf(X[4*g+1], rs, b), fmaf(X[16+4*g+1], rs, b));
        w.z = pkh(fmaf(X[4*g+2], rs, b), fmaf(X[16+4*g+2], rs, b));
        w.w = pkh(fmaf(X[4*g+3], rs, b), fmaf(X[16+4*g+3], rs, b));
        *(uint4*)&rp[(g ^ k) << 2] = w;
    }
}

// ---- prep: pre-pack all weights (f16, transposed, head-permuted) into ws ----
__global__ __launch_bounds__(64) void prep(
    const float* __restrict__ temb, const float* __restrict__ wq,
    const float* __restrict__ wk, const float* __restrict__ wv,
    const float* __restrict__ wo, const float* __restrict__ w1,
    const float* __restrict__ w2, unsigned int* __restrict__ ws)
{
    const int part = blockIdx.x;          // 0..24
    const int t = threadIdx.x;
    if (part == 24) {                     // TE tile
        for (int i = t; i < 256; i += 64) {
            int c = i >> 4, w = i & 15;
            ws[12288 + i] = (c < VOC) ? pkh(temb[c*32 + w], temb[c*32 + w + 16]) : 0u;
        }
        return;
    }
    const int L = part / 12, m = part % 12;
    unsigned int* o = ws + L * 6144;
    for (int i = t; i < 512; i += 64) {
        int c = i >> 4, w = i & 15;
        if (m < 3) {
            const float* M = (m == 0 ? wq : (m == 1 ? wk : wv)) + L*1024;
            int pc = permc(c);
            o[m*512 + i] = pkh(M[w*32 + pc], M[(w+16)*32 + pc]);
        } else if (m == 3) {
            const float* M = wo + L*1024;
            o[1536 + i] = pkh(M[permc(w)*32 + c], M[permc(w+16)*32 + c]);
        } else if (m < 8) {
            int q = m - 4;
            const float* M = w1 + L*4096;
            o[2048 + q*1024 + i] = pkh(M[w*128 + 32*q + c], M[(w+16)*128 + 32*q + c]);
        } else {
            int q = m - 8;
            const float* M = w2 + L*4096;
            o[2048 + q*1024 + 512 + i] = pkh(M[(32*q+w)*32 + c], M[(32*q+16+w)*32 + c]);
        }
    }
}

// w=3: reg budget ~170/wave (unified VGPR+AGPR). R6's w=5 (budget 102) -> 48 VGPR + 1GB
// scratch; R7's w=4 (budget 128) -> 64 VGPR + 370MB scratch. Demand is ~85-100 (R5: 84).
__global__ __launch_bounds__(THREADS, 3)
void tf_mfma(const int* __restrict__ toks, const float* __restrict__ temb,
             const float* __restrict__ pemb, const unsigned int* __restrict__ ws,
             float* __restrict__ out, int nelem)
{
    __shared__ unsigned int S[SMEM_U32];
    const int tid  = threadIdx.x;
    const int lane = tid & 63;
    const int wid  = tid >> 6;
    const int llo  = lane & 15, lhi = lane >> 4;
    const int boff = 4 * lhi;
    int le = lane / 6;
    int s  = lane - le * 6;
    if (le > 9) { le = 9; s = 5; }                   // 4 dup lanes/wave (in-bounds)
    const int rb   = wid*64 + le*6;                  // element's slot base (in-wave)
    const int myk  = (tid >> 1) & 3;
    const int elem = blockIdx.x * ELB + wid*10 + le;
    const f32x4 zz = {0.f, 0.f, 0.f, 0.f};

    float X[32];
    {
        const int ti  = (elem < nelem) ? (elem*SEQ + s) : 0;
        const int tok = toks[ti];
        #pragma unroll
        for (int g = 0; g < 8; ++g) {
            float4 a = *(const float4*)&temb[tok*32 + 4*g];
            float4 b = *(const float4*)&pemb[s*32 + 4*g];
            X[4*g+0] = a.x + b.x; X[4*g+1] = a.y + b.y;
            X[4*g+2] = a.z + b.z; X[4*g+3] = a.w + b.w;
        }
    }

    #pragma unroll 1
    for (int L = 0; L < NL; ++L) {
        const unsigned int* wsL = ws + L * 6144;

        ln_write(X, &S[XN], tid);                    // Xn (own slot)

        // ---- QKV (weights direct from global; all LDS traffic in-wave) ----
        uint4 q4[4];
        {
            h8 bq0 = ldh(wsL +          llo    *16 + boff);
            h8 bq1 = ldh(wsL +         (llo+16)*16 + boff);
            h8 bk0 = ldh(wsL +  512 +   llo    *16 + boff);
            h8 bk1 = ldh(wsL +  512 +  (llo+16)*16 + boff);
            h8 bv0 = ldh(wsL + 1024 +   llo    *16 + boff);
            h8 bv1 = ldh(wsL + 1024 +  (llo+16)*16 + boff);
            h8 aa[4];
            #pragma unroll
            for (int j = 0; j < 4; ++j) {
                int rowa = wid*64 + j*16 + llo;
                aa[j] = ldh(&S[XN + rowa*16 + swg(rowa, lhi)]);
            }
            #pragma unroll
            for (int j = 0; j < 4; ++j) {            // K -> KP
                f32x4 k0 = __builtin_amdgcn_mfma_f32_16x16x32_f16(aa[j], bk0, zz, 0,0,0);
                f32x4 k1 = __builtin_amdgcn_mfma_f32_16x16x32_f16(aa[j], bk1, zz, 0,0,0);
                int rowb = wid*64 + j*16 + lhi*4;
                #pragma unroll
                for (int rg = 0; rg < 4; ++rg) {
                    int row = rowb + rg;
                    S[KP + row*16 + swg(row, llo >> 2) + (llo & 3)] = pkh(k0[rg], k1[rg]);
                }
            }
            #pragma unroll
            for (int j = 0; j < 4; ++j) {            // Q -> XN (over Xn; aa read done)
                f32x4 qa = __builtin_amdgcn_mfma_f32_16x16x32_f16(aa[j], bq0, zz, 0,0,0);
                f32x4 qb = __builtin_amdgcn_mfma_f32_16x16x32_f16(aa[j], bq1, zz, 0,0,0);
                int rowb = wid*64 + j*16 + lhi*4;
                #pragma unroll
                for (int rg = 0; rg < 4; ++rg) {
                    int row = rowb + rg;
                    S[XN + row*16 + swg(row, llo >> 2) + (llo & 3)] = pkh(qa[rg], qb[rg]);
                }
            }
            #pragma unroll
            for (int h = 0; h < 4; ++h)              // own-row Q (in-wave RAW, in-order DS)
                q4[h] = *(const uint4*)&S[XN + tid*16 + ((h ^ myk) << 2)];
            #pragma unroll
            for (int j = 0; j < 4; ++j) {            // V -> XN (over Q; q4 reads issued)
                f32x4 v0 = __builtin_amdgcn_mfma_f32_16x16x32_f16(aa[j], bv0, zz, 0,0,0);
                f32x4 v1 = __builtin_amdgcn_mfma_f32_16x16x32_f16(aa[j], bv1, zz, 0,0,0);
                int rowb = wid*64 + j*16 + lhi*4;
                #pragma unroll
                for (int rg = 0; rg < 4; ++rg) {
                    int row = rowb + rg;
                    S[XN + row*16 + swg(row, llo >> 2) + (llo & 3)] = pkh(v0[rg], v1[rg]);
                }
            }
        }

        // ---- scores + softmax (K rows in-wave) ----
        float p[4][SEQ], rd[4];
        {
            float den[4] = {0.f, 0.f, 0.f, 0.f};
            #pragma unroll
            for (int t = 0; t < SEQ; ++t) {
                int krow = rb + t;
                const unsigned int* kr = &S[KP + krow*16];
                int kk4 = (krow >> 1) & 3;
                float msk = (t <= s) ? 0.f : -1e30f;
                #pragma unroll
                for (int h = 0; h < 4; ++h) {
                    uint4 kk = *(const uint4*)&kr[(h ^ kk4) << 2];
                    float d = dot2acc(q4[h].x, kk.x, 0.f);
                    d = dot2acc(q4[h].y, kk.y, d);
                    d = dot2acc(q4[h].z, kk.z, d);
                    d = dot2acc(q4[h].w, kk.w, d);
                    float e = __expf(fmaf(d, 0.35355339059327373f, msk));
                    p[h][t] = e; den[h] += e;
                }
            }
            #pragma unroll
            for (int h = 0; h < 4; ++h) rd[h] = __builtin_amdgcn_rcpf(den[h]);
        }
        // ---- PV (V rows in-wave) -> O -> KP own row (over K; score reads issued) ----
        {
            h2 O[16];
            #pragma unroll
            for (int w = 0; w < 16; ++w) O[w] = __builtin_bit_cast(h2, 0u);
            #pragma unroll
            for (int t = 0; t < SEQ; ++t) {
                int vrow = rb + t;
                const unsigned int* vr = &S[XN + vrow*16];
                int vk4 = (vrow >> 1) & 3;
                #pragma unroll
                for (int h = 0; h < 4; ++h) {
                    float wg = p[h][t] * rd[h];
                    h2 wg2 = __builtin_bit_cast(h2, pkh(wg, wg));
                    uint4 vv = *(const uint4*)&vr[(h ^ vk4) << 2];
                    O[4*h+0] += __builtin_bit_cast(h2, vv.x) * wg2;
                    O[4*h+1] += __builtin_bit_cast(h2, vv.y) * wg2;
                    O[4*h+2] += __builtin_bit_cast(h2, vv.z) * wg2;
                    O[4*h+3] += __builtin_bit_cast(h2, vv.w) * wg2;
                }
            }
            #pragma unroll
            for (int g = 0; g < 4; ++g) {
                uint4 w;
                w.x = __builtin_bit_cast(unsigned int, O[4*g+0]);
                w.y = __builtin_bit_cast(unsigned int, O[4*g+1]);
                w.z = __builtin_bit_cast(unsigned int, O[4*g+2]);
                w.w = __builtin_bit_cast(unsigned int, O[4*g+3]);
                *(uint4*)&S[KP + tid*16 + ((g ^ myk) << 2)] = w;
            }
        }

        // ---- O.Wo: A=KP(O) -> D=XN (over V; PV reads issued) ----
        {
            h8 bo0 = ldh(wsL + 1536 +  llo    *16 + boff);
            h8 bo1 = ldh(wsL + 1536 + (llo+16)*16 + boff);
            #pragma unroll
            for (int j = 0; j < 4; ++j) {
                int rowa = wid*64 + j*16 + llo;
                h8 a = ldh(&S[KP + rowa*16 + swg(rowa, lhi)]);
                f32x4 o0 = __builtin_amdgcn_mfma_f32_16x16x32_f16(a, bo0, zz, 0,0,0);
                f32x4 o1 = __builtin_amdgcn_mfma_f32_16x16x32_f16(a, bo1, zz, 0,0,0);
                int rowb = wid*64 + j*16 + lhi*4;
                #pragma unroll
                for (int rg = 0; rg < 4; ++rg) {
                    int row = rowb + rg;
                    S[XN + row*16 + swg(row, llo >> 2) + (llo & 3)] = pkh(o0[rg], o1[rg]);
                }
            }
        }
        #pragma unroll
        for (int g = 0; g < 4; ++g) {                // residual (own slot)
            uint4 v = *(const uint4*)&S[XN + tid*16 + ((g ^ myk) << 2)];
            X[4*g+0] += lo16(v.x); X[16+4*g+0] += hi16(v.x);
            X[4*g+1] += lo16(v.y); X[16+4*g+1] += hi16(v.y);
            X[4*g+2] += lo16(v.z); X[16+4*g+2] += hi16(v.z);
            X[4*g+3] += lo16(v.w); X[16+4*g+3] += hi16(v.w);
        }
        ln_write(X, &S[KP], tid);                    // Xn2 -> KP (over O; A reads issued)

        // ---- FFN: A=KP(Xn2), H->XN, FFN2 accumulates in regs ----
        f32x4 cf[4][2];
        #pragma unroll
        for (int j = 0; j < 4; ++j) { cf[j][0] = zz; cf[j][1] = zz; }
        #pragma unroll
        for (int q = 0; q < 4; ++q) {
            const unsigned int* wq4 = wsL + 2048 + q*1024;
            h8 b10 = ldh(wq4 +        llo    *16 + boff);
            h8 b11 = ldh(wq4 +       (llo+16)*16 + boff);
            h8 b20 = ldh(wq4 + 512 +  llo    *16 + boff);
            h8 b21 = ldh(wq4 + 512 + (llo+16)*16 + boff);
            #pragma unroll
            for (int j = 0; j < 4; ++j) {
                int rowa = wid*64 + j*16 + llo;
                h8 a = ldh(&S[KP + rowa*16 + swg(rowa, lhi)]);
                f32x4 h0 = __builtin_amdgcn_mfma_f32_16x16x32_f16(a, b10, zz, 0,0,0);
                f32x4 h1 = __builtin_amdgcn_mfma_f32_16x16x32_f16(a, b11, zz, 0,0,0);
                int rowb = wid*64 + j*16 + lhi*4;
                #pragma unroll
                for (int rg = 0; rg < 4; ++rg) {
                    int row = rowb + rg;
                    S[XN + row*16 + swg(row, llo >> 2) + (llo & 3)] =
                        pkh(gelu_f(h0[rg]), gelu_f(h1[rg]));
                }
            }
            #pragma unroll
            for (int j = 0; j < 4; ++j) {            // FFN2 (H rows in-wave)
                int rowa = wid*64 + j*16 + llo;
                h8 ah = ldh(&S[XN + rowa*16 + swg(rowa, lhi)]);
                cf[j][0] = __builtin_amdgcn_mfma_f32_16x16x32_f16(ah, b20, cf[j][0], 0,0,0);
                cf[j][1] = __builtin_amdgcn_mfma_f32_16x16x32_f16(ah, b21, cf[j][1], 0,0,0);
            }
        }
        #pragma unroll
        for (int j = 0; j < 4; ++j) {                // FFN2 out -> XN (over H)
            int rowb = wid*64 + j*16 + lhi*4;
            #pragma unroll
            for (int rg = 0; rg < 4; ++rg) {
                int row = rowb + rg;
                S[XN + row*16 + swg(row, llo >> 2) + (llo & 3)] = pkh(cf[j][0][rg], cf[j][1][rg]);
            }
        }
        #pragma unroll
        for (int g = 0; g < 4; ++g) {                // residual (own slot)
            uint4 v = *(const uint4*)&S[XN + tid*16 + ((g ^ myk) << 2)];
            X[4*g+0] += lo16(v.x); X[16+4*g+0] += hi16(v.x);
            X[4*g+1] += lo16(v.y); X[16+4*g+1] += hi16(v.y);
            X[4*g+2] += lo16(v.z); X[16+4*g+2] += hi16(v.z);
            X[4*g+3] += lo16(v.w); X[16+4*g+3] += hi16(v.w);
        }
    }

    // ---- final LN + weight-tied logits ----
    ln_write(X, &S[XN], tid);
    {
        h8 bt = ldh(ws + 12288 + llo*16 + boff);
        #pragma unroll
        for (int j = 0; j < 4; ++j) {
            int rowa = wid*64 + j*16 + llo;
            h8 a = ldh(&S[XN + rowa*16 + swg(rowa, lhi)]);
            f32x4 lg = __builtin_amdgcn_mfma_f32_16x16x32_f16(a, bt, zz, 0,0,0);
            int rowb = wid*64 + j*16 + lhi*4;
            #pragma unroll
            for (int rg = 0; rg < 4; ++rg) {
                int row = rowb + rg;
                S[KP + row*16 + swg(row, llo >> 2) + (llo & 3)] = __float_as_uint(lg[rg]);
            }
        }
    }
    __syncthreads();                                 // the only barrier
    {
        const long long obase = (long long)blockIdx.x * (ELB*SEQ*VOC);   // 3600
        const long long tot   = (long long)nelem * (SEQ*VOC);
        for (int i = tid; i < ELB*SEQ*VOC; i += THREADS) {
            if (obase + i < tot) {
                int rl   = i / VOC, col = i - rl*VOC;
                int w    = rl / 60, r6 = rl - w*60;
                int slot = w*64 + r6;
                out[obase + i] = __uint_as_float(
                    S[KP + slot*16 + (((col >> 2) ^ ((slot >> 1) & 3)) << 2) + (col & 3)]);
            }
        }
    }
}

extern "C" void kernel_launch(void* const* d_in, const int* in_sizes, int n_in,
                              void* d_out, int out_size, void* d_ws, size_t ws_size,
                              hipStream_t stream) {
    const int*   toks = (const int*)  d_in[0];
    const float* temb = (const float*)d_in[1];
    const float* pemb = (const float*)d_in[2];
    const float* wq   = (const float*)d_in[3];
    const float* wk   = (const float*)d_in[4];
    const float* wv   = (const float*)d_in[5];
    const float* wo   = (const float*)d_in[6];
    const float* w1   = (const float*)d_in[7];
    const float* w2   = (const float*)d_in[8];
    unsigned int* ws  = (unsigned int*)d_ws;         // 12544 u32 = 50 KB used
    float* out = (float*)d_out;
    const int nelem = in_sizes[0] / SEQ;             // 131072
    const int nblk  = (nelem + ELB - 1) / ELB;       // 3277

    prep<<<dim3(25), dim3(64), 0, stream>>>(temb, wq, wk, wv, wo, w1, w2, ws);
    tf_mfma<<<dim3(nblk), dim3(THREADS), 0, stream>>>(toks, temb, pemb, ws, out, nelem);
}

// Round 9
// 145.209 us; speedup vs baseline: 1.9165x; 1.0707x over previous
//
#include <hip/hip_runtime.h>

#define SEQ 6
#define THREADS 256              // 4 waves; 10 elements per wave (60 active lanes)
#define ELB 40                   // elements per block
#define NL 2
#define VOC 15

typedef __attribute__((ext_vector_type(8))) _Float16 h8;
typedef __attribute__((ext_vector_type(2))) _Float16 h2;
typedef __attribute__((ext_vector_type(4))) float    f32x4;

// LDS: 2 pools x 256 slots x 16 u32, XOR-swizzled 16B groups. 8192 u32 = 32 KB.
// Slot = tid (wave w owns slots 64w..64w+63). All intra-layer traffic is
// within-wave (in-order DS pipe) -> zero barriers until logits staging.
#define XN 0          // Xn -> Q -> V -> OWo -> H -> FFN2
#define KP 4096       // K -> O -> Xn2 -> logits f32
#define SMEM_U32 8192

// ws layout (u32): per layer L at L*6144: Wq 0, Wk 512, Wv 1024, Wo 1536,
// quarter q: 2048+q*1024 (W1q at +0, W2q at +512). TE at 12288 (256).

__device__ __forceinline__ unsigned int pkh(float a, float b) {
    auto h = __builtin_amdgcn_cvt_pkrtz(a, b);
    return __builtin_bit_cast(unsigned int, h);
}
__device__ __forceinline__ float lo16(unsigned int u) {
    h2 h = __builtin_bit_cast(h2, u); return (float)h.x;
}
__device__ __forceinline__ float hi16(unsigned int u) {
    h2 h = __builtin_bit_cast(h2, u); return (float)h.y;
}
__device__ __forceinline__ h8 ldh(const unsigned int* p) {
    uint4 u = *(const uint4*)p;
    return __builtin_bit_cast(h8, u);
}
#if __has_builtin(__builtin_amdgcn_fdot2)
__device__ __forceinline__ float dot2acc(unsigned int a, unsigned int b, float c) {
    return __builtin_amdgcn_fdot2(__builtin_bit_cast(h2, a), __builtin_bit_cast(h2, b), c, false);
}
#else
__device__ __forceinline__ float dot2acc(unsigned int a, unsigned int b, float c) {
    return fmaf(hi16(a), hi16(b), fmaf(lo16(a), lo16(b), c));
}
#endif
// GELU via clamped odd polynomial (NO transcendentals; exp+rcp were quarter-rate,
// ~40% of all VALU cycles). t(x)=xc*P(xc^2) fits erf(x/sqrt2) on |x|<=3 to |err|<=3e-3
// (Chebyshev-node divided-difference fit); input-clamp tail err <=5e-3 at |x|=6.
__device__ __forceinline__ float gelu_f(float x) {
#if __has_builtin(__builtin_amdgcn_fmed3f)
    float xc = __builtin_amdgcn_fmed3f(x, -3.0f, 3.0f);
#else
    float xc = fminf(fmaxf(x, -3.0f), 3.0f);
#endif
    float u = xc * xc;
    float p = fmaf(fmaf(fmaf(fmaf(4.80757e-5f, u, -1.40632e-3f), u,
                              1.75795e-2f), u, -1.30947e-1f), u, 7.9714e-1f);
    float hx = 0.5f * x;
    return fmaf(hx * xc, p, hx);                 // 0.5x(1 + xc*P(u))
}
__device__ __forceinline__ int permc(int p) {        // head-local sigma pairs
    int h = (p & 15) >> 2, j = p & 3, hi = p >> 4;
    return 8*h + 2*j + hi;
}
__device__ __forceinline__ int swg(int row, int g) { // swizzled 16B-group offset
    return ((g ^ ((row >> 1) & 3)) << 2);
}
__device__ __forceinline__ void ln_write(const float* X, unsigned int* base, int row) {
    float mu = 0.f;
    #pragma unroll
    for (int c = 0; c < 32; ++c) mu += X[c];
    mu *= 0.03125f;
    float var = 0.f;
    #pragma unroll
    for (int c = 0; c < 32; ++c) { float d = X[c] - mu; var += d * d; }
    var *= 0.03125f;
    float rs = rsqrtf(var + 1e-5f), b = -mu * rs;
    unsigned int* rp = base + row * 16;
    const int k = (row >> 1) & 3;
    #pragma unroll
    for (int g = 0; g < 4; ++g) {
        uint4 w;
        w.x = pkh(fmaf(X[4*g+0], rs, b), fmaf(X[16+4*g+0], rs, b));
        w.y = pkh(fmaf(X[4*g+1], rs, b), fmaf(X[16+4*g+1], rs, b));
        w.z = pkh(fmaf(X[4*g+2], rs, b), fmaf(X[16+4*g+2], rs, b));
        w.w = pkh(fmaf(X[4*g+3], rs, b), fmaf(X[16+4*g+3], rs, b));
        *(uint4*)&rp[(g ^ k) << 2] = w;
    }
}

// ---- prep: pre-pack all weights (f16, transposed, head-permuted) into ws ----
__global__ __launch_bounds__(64) void prep(
    const float* __restrict__ temb, const float* __restrict__ wq,
    const float* __restrict__ wk, const float* __restrict__ wv,
    const float* __restrict__ wo, const float* __restrict__ w1,
    const float* __restrict__ w2, unsigned int* __restrict__ ws)
{
    const int part = blockIdx.x;          // 0..24
    const int t = threadIdx.x;
    if (part == 24) {                     // TE tile
        for (int i = t; i < 256; i += 64) {
            int c = i >> 4, w = i & 15;
            ws[12288 + i] = (c < VOC) ? pkh(temb[c*32 + w], temb[c*32 + w + 16]) : 0u;
        }
        return;
    }
    const int L = part / 12, m = part % 12;
    unsigned int* o = ws + L * 6144;
    for (int i = t; i < 512; i += 64) {
        int c = i >> 4, w = i & 15;
        if (m < 3) {
            const float* M = (m == 0 ? wq : (m == 1 ? wk : wv)) + L*1024;
            int pc = permc(c);
            o[m*512 + i] = pkh(M[w*32 + pc], M[(w+16)*32 + pc]);
        } else if (m == 3) {
            const float* M = wo + L*1024;
            o[1536 + i] = pkh(M[permc(w)*32 + c], M[permc(w+16)*32 + c]);
        } else if (m < 8) {
            int q = m - 4;
            const float* M = w1 + L*4096;
            o[2048 + q*1024 + i] = pkh(M[w*128 + 32*q + c], M[(w+16)*128 + 32*q + c]);
        } else {
            int q = m - 8;
            const float* M = w2 + L*4096;
            o[2048 + q*1024 + 512 + i] = pkh(M[(32*q+w)*32 + c], M[(32*q+16+w)*32 + c]);
        }
    }
}

// w=3: reg budget ~170/wave (unified VGPR+AGPR; measured demand ~84 arch + accs).
// w=4 (128) forces 64-arch clamp + scratch spill (R7); w=5 (102) worse (R6).
__global__ __launch_bounds__(THREADS, 3)
void tf_mfma(const int* __restrict__ toks, const float* __restrict__ temb,
             const float* __restrict__ pemb, const unsigned int* __restrict__ ws,
             float* __restrict__ out, int nelem)
{
    __shared__ unsigned int S[SMEM_U32];
    const int tid  = threadIdx.x;
    const int lane = tid & 63;
    const int wid  = tid >> 6;
    const int llo  = lane & 15, lhi = lane >> 4;
    const int boff = 4 * lhi;
    int le = lane / 6;
    int s  = lane - le * 6;
    if (le > 9) { le = 9; s = 5; }                   // 4 dup lanes/wave (in-bounds)
    const int rb   = wid*64 + le*6;                  // element's slot base (in-wave)
    const int myk  = (tid >> 1) & 3;
    const int elem = blockIdx.x * ELB + wid*10 + le;
    const f32x4 zz = {0.f, 0.f, 0.f, 0.f};

    float X[32];
    {
        const int ti  = (elem < nelem) ? (elem*SEQ + s) : 0;
        const int tok = toks[ti];
        #pragma unroll
        for (int g = 0; g < 8; ++g) {
            float4 a = *(const float4*)&temb[tok*32 + 4*g];
            float4 b = *(const float4*)&pemb[s*32 + 4*g];
            X[4*g+0] = a.x + b.x; X[4*g+1] = a.y + b.y;
            X[4*g+2] = a.z + b.z; X[4*g+3] = a.w + b.w;
        }
    }

    #pragma unroll 1
    for (int L = 0; L < NL; ++L) {
        const unsigned int* wsL = ws + L * 6144;

        ln_write(X, &S[XN], tid);                    // Xn (own slot)

        // ---- QKV (weights direct from global; all LDS traffic in-wave) ----
        uint4 q4[4];
        {
            h8 bq0 = ldh(wsL +          llo    *16 + boff);
            h8 bq1 = ldh(wsL +         (llo+16)*16 + boff);
            h8 bk0 = ldh(wsL +  512 +   llo    *16 + boff);
            h8 bk1 = ldh(wsL +  512 +  (llo+16)*16 + boff);
            h8 bv0 = ldh(wsL + 1024 +   llo    *16 + boff);
            h8 bv1 = ldh(wsL + 1024 +  (llo+16)*16 + boff);
            h8 aa[4];
            #pragma unroll
            for (int j = 0; j < 4; ++j) {
                int rowa = wid*64 + j*16 + llo;
                aa[j] = ldh(&S[XN + rowa*16 + swg(rowa, lhi)]);
            }
            #pragma unroll
            for (int j = 0; j < 4; ++j) {            // K -> KP
                f32x4 k0 = __builtin_amdgcn_mfma_f32_16x16x32_f16(aa[j], bk0, zz, 0,0,0);
                f32x4 k1 = __builtin_amdgcn_mfma_f32_16x16x32_f16(aa[j], bk1, zz, 0,0,0);
                int rowb = wid*64 + j*16 + lhi*4;
                #pragma unroll
                for (int rg = 0; rg < 4; ++rg) {
                    int row = rowb + rg;
                    S[KP + row*16 + swg(row, llo >> 2) + (llo & 3)] = pkh(k0[rg], k1[rg]);
                }
            }
            #pragma unroll
            for (int j = 0; j < 4; ++j) {            // Q -> XN (over Xn; aa read done)
                f32x4 qa = __builtin_amdgcn_mfma_f32_16x16x32_f16(aa[j], bq0, zz, 0,0,0);
                f32x4 qb = __builtin_amdgcn_mfma_f32_16x16x32_f16(aa[j], bq1, zz, 0,0,0);
                int rowb = wid*64 + j*16 + lhi*4;
                #pragma unroll
                for (int rg = 0; rg < 4; ++rg) {
                    int row = rowb + rg;
                    S[XN + row*16 + swg(row, llo >> 2) + (llo & 3)] = pkh(qa[rg], qb[rg]);
                }
            }
            #pragma unroll
            for (int h = 0; h < 4; ++h)              // own-row Q (in-wave RAW, in-order DS)
                q4[h] = *(const uint4*)&S[XN + tid*16 + ((h ^ myk) << 2)];
            #pragma unroll
            for (int j = 0; j < 4; ++j) {            // V -> XN (over Q; q4 reads issued)
                f32x4 v0 = __builtin_amdgcn_mfma_f32_16x16x32_f16(aa[j], bv0, zz, 0,0,0);
                f32x4 v1 = __builtin_amdgcn_mfma_f32_16x16x32_f16(aa[j], bv1, zz, 0,0,0);
                int rowb = wid*64 + j*16 + lhi*4;
                #pragma unroll
                for (int rg = 0; rg < 4; ++rg) {
                    int row = rowb + rg;
                    S[XN + row*16 + swg(row, llo >> 2) + (llo & 3)] = pkh(v0[rg], v1[rg]);
                }
            }
        }

        // ---- scores + softmax (K rows in-wave) ----
        float p[4][SEQ], rd[4];
        {
            float den[4] = {0.f, 0.f, 0.f, 0.f};
            #pragma unroll
            for (int t = 0; t < SEQ; ++t) {
                int krow = rb + t;
                const unsigned int* kr = &S[KP + krow*16];
                int kk4 = (krow >> 1) & 3;
                float msk = (t <= s) ? 0.f : -1e30f;
                #pragma unroll
                for (int h = 0; h < 4; ++h) {
                    uint4 kk = *(const uint4*)&kr[(h ^ kk4) << 2];
                    float d = dot2acc(q4[h].x, kk.x, 0.f);
                    d = dot2acc(q4[h].y, kk.y, d);
                    d = dot2acc(q4[h].z, kk.z, d);
                    d = dot2acc(q4[h].w, kk.w, d);
                    float e = __expf(fmaf(d, 0.35355339059327373f, msk));
                    p[h][t] = e; den[h] += e;
                }
            }
            #pragma unroll
            for (int h = 0; h < 4; ++h) rd[h] = __builtin_amdgcn_rcpf(den[h]);
        }
        // ---- PV (V rows in-wave) -> O -> KP own row (over K; score reads issued) ----
        {
            h2 O[16];
            #pragma unroll
            for (int w = 0; w < 16; ++w) O[w] = __builtin_bit_cast(h2, 0u);
            #pragma unroll
            for (int t = 0; t < SEQ; ++t) {
                int vrow = rb + t;
                const unsigned int* vr = &S[XN + vrow*16];
                int vk4 = (vrow >> 1) & 3;
                #pragma unroll
                for (int h = 0; h < 4; ++h) {
                    float wg = p[h][t] * rd[h];
                    h2 wg2 = __builtin_bit_cast(h2, pkh(wg, wg));
                    uint4 vv = *(const uint4*)&vr[(h ^ vk4) << 2];
                    O[4*h+0] += __builtin_bit_cast(h2, vv.x) * wg2;
                    O[4*h+1] += __builtin_bit_cast(h2, vv.y) * wg2;
                    O[4*h+2] += __builtin_bit_cast(h2, vv.z) * wg2;
                    O[4*h+3] += __builtin_bit_cast(h2, vv.w) * wg2;
                }
            }
            #pragma unroll
            for (int g = 0; g < 4; ++g) {
                uint4 w;
                w.x = __builtin_bit_cast(unsigned int, O[4*g+0]);
                w.y = __builtin_bit_cast(unsigned int, O[4*g+1]);
                w.z = __builtin_bit_cast(unsigned int, O[4*g+2]);
                w.w = __builtin_bit_cast(unsigned int, O[4*g+3]);
                *(uint4*)&S[KP + tid*16 + ((g ^ myk) << 2)] = w;
            }
        }

        // ---- O.Wo: A=KP(O) -> D=XN (over V; PV reads issued) ----
        {
            h8 bo0 = ldh(wsL + 1536 +  llo    *16 + boff);
            h8 bo1 = ldh(wsL + 1536 + (llo+16)*16 + boff);
            #pragma unroll
            for (int j = 0; j < 4; ++j) {
                int rowa = wid*64 + j*16 + llo;
                h8 a = ldh(&S[KP + rowa*16 + swg(rowa, lhi)]);
                f32x4 o0 = __builtin_amdgcn_mfma_f32_16x16x32_f16(a, bo0, zz, 0,0,0);
                f32x4 o1 = __builtin_amdgcn_mfma_f32_16x16x32_f16(a, bo1, zz, 0,0,0);
                int rowb = wid*64 + j*16 + lhi*4;
                #pragma unroll
                for (int rg = 0; rg < 4; ++rg) {
                    int row = rowb + rg;
                    S[XN + row*16 + swg(row, llo >> 2) + (llo & 3)] = pkh(o0[rg], o1[rg]);
                }
            }
        }
        #pragma unroll
        for (int g = 0; g < 4; ++g) {                // residual (own slot)
            uint4 v = *(const uint4*)&S[XN + tid*16 + ((g ^ myk) << 2)];
            X[4*g+0] += lo16(v.x); X[16+4*g+0] += hi16(v.x);
            X[4*g+1] += lo16(v.y); X[16+4*g+1] += hi16(v.y);
            X[4*g+2] += lo16(v.z); X[16+4*g+2] += hi16(v.z);
            X[4*g+3] += lo16(v.w); X[16+4*g+3] += hi16(v.w);
        }
        ln_write(X, &S[KP], tid);                    // Xn2 -> KP (over O; A reads issued)

        // ---- FFN: A=KP(Xn2), H->XN, FFN2 accumulates in regs ----
        f32x4 cf[4][2];
        #pragma unroll
        for (int j = 0; j < 4; ++j) { cf[j][0] = zz; cf[j][1] = zz; }
        #pragma unroll
        for (int q = 0; q < 4; ++q) {
            const unsigned int* wq4 = wsL + 2048 + q*1024;
            h8 b10 = ldh(wq4 +        llo    *16 + boff);
            h8 b11 = ldh(wq4 +       (llo+16)*16 + boff);
            h8 b20 = ldh(wq4 + 512 +  llo    *16 + boff);
            h8 b21 = ldh(wq4 + 512 + (llo+16)*16 + boff);
            #pragma unroll
            for (int j = 0; j < 4; ++j) {
                int rowa = wid*64 + j*16 + llo;
                h8 a = ldh(&S[KP + rowa*16 + swg(rowa, lhi)]);
                f32x4 h0 = __builtin_amdgcn_mfma_f32_16x16x32_f16(a, b10, zz, 0,0,0);
                f32x4 h1 = __builtin_amdgcn_mfma_f32_16x16x32_f16(a, b11, zz, 0,0,0);
                int rowb = wid*64 + j*16 + lhi*4;
                #pragma unroll
                for (int rg = 0; rg < 4; ++rg) {
                    int row = rowb + rg;
                    S[XN + row*16 + swg(row, llo >> 2) + (llo & 3)] =
                        pkh(gelu_f(h0[rg]), gelu_f(h1[rg]));
                }
            }
            #pragma unroll
            for (int j = 0; j < 4; ++j) {            // FFN2 (H rows in-wave)
                int rowa = wid*64 + j*16 + llo;
                h8 ah = ldh(&S[XN + rowa*16 + swg(rowa, lhi)]);
                cf[j][0] = __builtin_amdgcn_mfma_f32_16x16x32_f16(ah, b20, cf[j][0], 0,0,0);
                cf[j][1] = __builtin_amdgcn_mfma_f32_16x16x32_f16(ah, b21, cf[j][1], 0,0,0);
            }
        }
        #pragma unroll
        for (int j = 0; j < 4; ++j) {                // FFN2 out -> XN (over H)
            int rowb = wid*64 + j*16 + lhi*4;
            #pragma unroll
            for (int rg = 0; rg < 4; ++rg) {
                int row = rowb + rg;
                S[XN + row*16 + swg(row, llo >> 2) + (llo & 3)] = pkh(cf[j][0][rg], cf[j][1][rg]);
            }
        }
        #pragma unroll
        for (int g = 0; g < 4; ++g) {                // residual (own slot)
            uint4 v = *(const uint4*)&S[XN + tid*16 + ((g ^ myk) << 2)];
            X[4*g+0] += lo16(v.x); X[16+4*g+0] += hi16(v.x);
            X[4*g+1] += lo16(v.y); X[16+4*g+1] += hi16(v.y);
            X[4*g+2] += lo16(v.z); X[16+4*g+2] += hi16(v.z);
            X[4*g+3] += lo16(v.w); X[16+4*g+3] += hi16(v.w);
        }
    }

    // ---- final LN + weight-tied logits ----
    ln_write(X, &S[XN], tid);
    {
        h8 bt = ldh(ws + 12288 + llo*16 + boff);
        #pragma unroll
        for (int j = 0; j < 4; ++j) {
            int rowa = wid*64 + j*16 + llo;
            h8 a = ldh(&S[XN + rowa*16 + swg(rowa, lhi)]);
            f32x4 lg = __builtin_amdgcn_mfma_f32_16x16x32_f16(a, bt, zz, 0,0,0);
            int rowb = wid*64 + j*16 + lhi*4;
            #pragma unroll
            for (int rg = 0; rg < 4; ++rg) {
                int row = rowb + rg;
                S[KP + row*16 + swg(row, llo >> 2) + (llo & 3)] = __float_as_uint(lg[rg]);
            }
        }
    }
    __syncthreads();                                 // the only barrier
    {
        const long long obase = (long long)blockIdx.x * (ELB*SEQ*VOC);   // 3600
        const long long tot   = (long long)nelem * (SEQ*VOC);
        for (int i = tid; i < ELB*SEQ*VOC; i += THREADS) {
            if (obase + i < tot) {
                int rl   = i / VOC, col = i - rl*VOC;
                int w    = rl / 60, r6 = rl - w*60;
                int slot = w*64 + r6;
                out[obase + i] = __uint_as_float(
                    S[KP + slot*16 + (((col >> 2) ^ ((slot >> 1) & 3)) << 2) + (col & 3)]);
            }
        }
    }
}

extern "C" void kernel_launch(void* const* d_in, const int* in_sizes, int n_in,
                              void* d_out, int out_size, void* d_ws, size_t ws_size,
                              hipStream_t stream) {
    const int*   toks = (const int*)  d_in[0];
    const float* temb = (const float*)d_in[1];
    const float* pemb = (const float*)d_in[2];
    const float* wq   = (const float*)d_in[3];
    const float* wk   = (const float*)d_in[4];
    const float* wv   = (const float*)d_in[5];
    const float* wo   = (const float*)d_in[6];
    const float* w1   = (const float*)d_in[7];
    const float* w2   = (const float*)d_in[8];
    unsigned int* ws  = (unsigned int*)d_ws;         // 12544 u32 = 50 KB used
    float* out = (float*)d_out;
    const int nelem = in_sizes[0] / SEQ;             // 131072
    const int nblk  = (nelem + ELB - 1) / ELB;       // 3277

    prep<<<dim3(25), dim3(64), 0, stream>>>(temb, wq, wk, wv, wo, w1, w2, ws);
    tf_mfma<<<dim3(nblk), dim3(THREADS), 0, stream>>>(toks, temb, pemb, ws, out, nelem);
}

// Round 10
// 144.298 us; speedup vs baseline: 1.9286x; 1.0063x over previous
//
#include <hip/hip_runtime.h>

#define SEQ 6
#define THREADS 256              // 4 waves; 10 elements per wave (60 active lanes)
#define ELB 40                   // elements per block
#define NL 2
#define VOC 15

typedef __attribute__((ext_vector_type(8))) _Float16 h8;
typedef __attribute__((ext_vector_type(2))) _Float16 h2;
typedef __attribute__((ext_vector_type(4))) float    f32x4;

// LDS: 2 pools x 256 slots x 16 u32, XOR-swizzled 16B groups. 8192 u32 = 32 KB.
// Slot = tid (wave w owns slots 64w..64w+63). All intra-layer traffic is
// within-wave (in-order DS pipe) -> zero barriers until logits staging.
#define XN 0          // Xn -> Q -> V -> OWo -> H -> FFN2
#define KP 4096       // K -> O -> Xn2 -> logits f32
#define SMEM_U32 8192

// ws layout (u32): per layer L at L*6144: Wq 0, Wk 512, Wv 1024, Wo 1536,
// quarter q: 2048+q*1024 (W1q at +0, W2q at +512). TE at 12288 (256).

__device__ __forceinline__ unsigned int pkh(float a, float b) {
    auto h = __builtin_amdgcn_cvt_pkrtz(a, b);
    return __builtin_bit_cast(unsigned int, h);
}
__device__ __forceinline__ float lo16(unsigned int u) {
    h2 h = __builtin_bit_cast(h2, u); return (float)h.x;
}
__device__ __forceinline__ float hi16(unsigned int u) {
    h2 h = __builtin_bit_cast(h2, u); return (float)h.y;
}
__device__ __forceinline__ h8 ldh(const unsigned int* p) {
    uint4 u = *(const uint4*)p;
    return __builtin_bit_cast(h8, u);
}
#if __has_builtin(__builtin_amdgcn_fdot2)
__device__ __forceinline__ float dot2acc(unsigned int a, unsigned int b, float c) {
    return __builtin_amdgcn_fdot2(__builtin_bit_cast(h2, a), __builtin_bit_cast(h2, b), c, false);
}
#else
__device__ __forceinline__ float dot2acc(unsigned int a, unsigned int b, float c) {
    return fmaf(hi16(a), hi16(b), fmaf(lo16(a), lo16(b), c));
}
#endif
// GELU via clamped odd polynomial (NO transcendentals). Kept in f32: the c4
// coefficient is f16-subnormal, so a packed-f16 version would lose ~1e-2 acc.
__device__ __forceinline__ float gelu_f(float x) {
#if __has_builtin(__builtin_amdgcn_fmed3f)
    float xc = __builtin_amdgcn_fmed3f(x, -3.0f, 3.0f);
#else
    float xc = fminf(fmaxf(x, -3.0f), 3.0f);
#endif
    float u = xc * xc;
    float p = fmaf(fmaf(fmaf(fmaf(4.80757e-5f, u, -1.40632e-3f), u,
                              1.75795e-2f), u, -1.30947e-1f), u, 7.9714e-1f);
    float hx = 0.5f * x;
    return fmaf(hx * xc, p, hx);                 // 0.5x(1 + xc*P(u))
}
__device__ __forceinline__ int permc(int p) {        // head-local sigma pairs
    int h = (p & 15) >> 2, j = p & 3, hi = p >> 4;
    return 8*h + 2*j + hi;
}
__device__ __forceinline__ int swg(int row, int g) { // swizzled 16B-group offset
    return ((g ^ ((row >> 1) & 3)) << 2);
}
__device__ __forceinline__ void ln_write(const float* X, unsigned int* base, int row) {
    float mu = 0.f;
    #pragma unroll
    for (int c = 0; c < 32; ++c) mu += X[c];
    mu *= 0.03125f;
    float var = 0.f;
    #pragma unroll
    for (int c = 0; c < 32; ++c) { float d = X[c] - mu; var += d * d; }
    var *= 0.03125f;
    float rs = rsqrtf(var + 1e-5f), b = -mu * rs;
    unsigned int* rp = base + row * 16;
    const int k = (row >> 1) & 3;
    #pragma unroll
    for (int g = 0; g < 4; ++g) {
        uint4 w;
        w.x = pkh(fmaf(X[4*g+0], rs, b), fmaf(X[16+4*g+0], rs, b));
        w.y = pkh(fmaf(X[4*g+1], rs, b), fmaf(X[16+4*g+1], rs, b));
        w.z = pkh(fmaf(X[4*g+2], rs, b), fmaf(X[16+4*g+2], rs, b));
        w.w = pkh(fmaf(X[4*g+3], rs, b), fmaf(X[16+4*g+3], rs, b));
        *(uint4*)&rp[(g ^ k) << 2] = w;
    }
}

// ---- prep: pre-pack all weights (f16, transposed, head-permuted) into ws ----
__global__ __launch_bounds__(64) void prep(
    const float* __restrict__ temb, const float* __restrict__ wq,
    const float* __restrict__ wk, const float* __restrict__ wv,
    const float* __restrict__ wo, const float* __restrict__ w1,
    const float* __restrict__ w2, unsigned int* __restrict__ ws)
{
    const int part = blockIdx.x;          // 0..24
    const int t = threadIdx.x;
    if (part == 24) {                     // TE tile
        for (int i = t; i < 256; i += 64) {
            int c = i >> 4, w = i & 15;
            ws[12288 + i] = (c < VOC) ? pkh(temb[c*32 + w], temb[c*32 + w + 16]) : 0u;
        }
        return;
    }
    const int L = part / 12, m = part % 12;
    unsigned int* o = ws + L * 6144;
    for (int i = t; i < 512; i += 64) {
        int c = i >> 4, w = i & 15;
        if (m < 3) {
            const float* M = (m == 0 ? wq : (m == 1 ? wk : wv)) + L*1024;
            int pc = permc(c);
            o[m*512 + i] = pkh(M[w*32 + pc], M[(w+16)*32 + pc]);
        } else if (m == 3) {
            const float* M = wo + L*1024;
            o[1536 + i] = pkh(M[permc(w)*32 + c], M[permc(w+16)*32 + c]);
        } else if (m < 8) {
            int q = m - 4;
            const float* M = w1 + L*4096;
            o[2048 + q*1024 + i] = pkh(M[w*128 + 32*q + c], M[(w+16)*128 + 32*q + c]);
        } else {
            int q = m - 8;
            const float* M = w2 + L*4096;
            o[2048 + q*1024 + 512 + i] = pkh(M[(32*q+w)*32 + c], M[(32*q+16+w)*32 + c]);
        }
    }
}

// w=3: reg budget ~170/wave (unified VGPR+AGPR). Allocator is demand-driven, so if
// the online-softmax merge drops total allocation <=128, HW residency becomes
// 4 waves/SIMD automatically -- without the w=4 spill cliff (R7).
__global__ __launch_bounds__(THREADS, 3)
void tf_mfma(const int* __restrict__ toks, const float* __restrict__ temb,
             const float* __restrict__ pemb, const unsigned int* __restrict__ ws,
             float* __restrict__ out, int nelem)
{
    __shared__ unsigned int S[SMEM_U32];
    const int tid  = threadIdx.x;
    const int lane = tid & 63;
    const int wid  = tid >> 6;
    const int llo  = lane & 15, lhi = lane >> 4;
    const int boff = 4 * lhi;
    int le = lane / 6;
    int s  = lane - le * 6;
    if (le > 9) { le = 9; s = 5; }                   // 4 dup lanes/wave (in-bounds)
    const int rb   = wid*64 + le*6;                  // element's slot base (in-wave)
    const int myk  = (tid >> 1) & 3;
    const int elem = blockIdx.x * ELB + wid*10 + le;
    const f32x4 zz = {0.f, 0.f, 0.f, 0.f};

    float X[32];
    {
        const int ti  = (elem < nelem) ? (elem*SEQ + s) : 0;
        const int tok = toks[ti];
        #pragma unroll
        for (int g = 0; g < 8; ++g) {
            float4 a = *(const float4*)&temb[tok*32 + 4*g];
            float4 b = *(const float4*)&pemb[s*32 + 4*g];
            X[4*g+0] = a.x + b.x; X[4*g+1] = a.y + b.y;
            X[4*g+2] = a.z + b.z; X[4*g+3] = a.w + b.w;
        }
    }

    #pragma unroll 1
    for (int L = 0; L < NL; ++L) {
        const unsigned int* wsL = ws + L * 6144;

        ln_write(X, &S[XN], tid);                    // Xn (own slot)

        // ---- QKV (weights direct from global; all LDS traffic in-wave) ----
        uint4 q4[4];
        {
            h8 bq0 = ldh(wsL +          llo    *16 + boff);
            h8 bq1 = ldh(wsL +         (llo+16)*16 + boff);
            h8 bk0 = ldh(wsL +  512 +   llo    *16 + boff);
            h8 bk1 = ldh(wsL +  512 +  (llo+16)*16 + boff);
            h8 bv0 = ldh(wsL + 1024 +   llo    *16 + boff);
            h8 bv1 = ldh(wsL + 1024 +  (llo+16)*16 + boff);
            h8 aa[4];
            #pragma unroll
            for (int j = 0; j < 4; ++j) {
                int rowa = wid*64 + j*16 + llo;
                aa[j] = ldh(&S[XN + rowa*16 + swg(rowa, lhi)]);
            }
            #pragma unroll
            for (int j = 0; j < 4; ++j) {            // K -> KP
                f32x4 k0 = __builtin_amdgcn_mfma_f32_16x16x32_f16(aa[j], bk0, zz, 0,0,0);
                f32x4 k1 = __builtin_amdgcn_mfma_f32_16x16x32_f16(aa[j], bk1, zz, 0,0,0);
                int rowb = wid*64 + j*16 + lhi*4;
                #pragma unroll
                for (int rg = 0; rg < 4; ++rg) {
                    int row = rowb + rg;
                    S[KP + row*16 + swg(row, llo >> 2) + (llo & 3)] = pkh(k0[rg], k1[rg]);
                }
            }
            #pragma unroll
            for (int j = 0; j < 4; ++j) {            // Q -> XN (over Xn; aa read done)
                f32x4 qa = __builtin_amdgcn_mfma_f32_16x16x32_f16(aa[j], bq0, zz, 0,0,0);
                f32x4 qb = __builtin_amdgcn_mfma_f32_16x16x32_f16(aa[j], bq1, zz, 0,0,0);
                int rowb = wid*64 + j*16 + lhi*4;
                #pragma unroll
                for (int rg = 0; rg < 4; ++rg) {
                    int row = rowb + rg;
                    S[XN + row*16 + swg(row, llo >> 2) + (llo & 3)] = pkh(qa[rg], qb[rg]);
                }
            }
            #pragma unroll
            for (int h = 0; h < 4; ++h)              // own-row Q (in-wave RAW, in-order DS)
                q4[h] = *(const uint4*)&S[XN + tid*16 + ((h ^ myk) << 2)];
            #pragma unroll
            for (int j = 0; j < 4; ++j) {            // V -> XN (over Q; q4 reads issued)
                f32x4 v0 = __builtin_amdgcn_mfma_f32_16x16x32_f16(aa[j], bv0, zz, 0,0,0);
                f32x4 v1 = __builtin_amdgcn_mfma_f32_16x16x32_f16(aa[j], bv1, zz, 0,0,0);
                int rowb = wid*64 + j*16 + lhi*4;
                #pragma unroll
                for (int rg = 0; rg < 4; ++rg) {
                    int row = rowb + rg;
                    S[XN + row*16 + swg(row, llo >> 2) + (llo & 3)] = pkh(v0[rg], v1[rg]);
                }
            }
        }

        // ---- attention: ONLINE scores+PV in one pass (no p[4][6] storage) ----
        // O_acc = sum_t e_t * V_t, den = sum_t e_t; normalize once at the end.
        // Masked t: e = exp(-1e30) = 0 contributes nothing (branch-free).
        {
            float den[4] = {0.f, 0.f, 0.f, 0.f};
            h2 O[16];
            #pragma unroll
            for (int w = 0; w < 16; ++w) O[w] = __builtin_bit_cast(h2, 0u);
            #pragma unroll
            for (int t = 0; t < SEQ; ++t) {
                int krow = rb + t;
                const unsigned int* kr = &S[KP + krow*16];
                const unsigned int* vr = &S[XN + krow*16];
                int kk4 = (krow >> 1) & 3;
                float msk = (t <= s) ? 0.f : -1e30f;
                #pragma unroll
                for (int h = 0; h < 4; ++h) {
                    uint4 kk = *(const uint4*)&kr[(h ^ kk4) << 2];
                    float d = dot2acc(q4[h].x, kk.x, 0.f);
                    d = dot2acc(q4[h].y, kk.y, d);
                    d = dot2acc(q4[h].z, kk.z, d);
                    d = dot2acc(q4[h].w, kk.w, d);
                    float e = __expf(fmaf(d, 0.35355339059327373f, msk));
                    den[h] += e;
                    h2 wg2 = __builtin_bit_cast(h2, pkh(e, e));
                    uint4 vv = *(const uint4*)&vr[(h ^ kk4) << 2];
                    O[4*h+0] += __builtin_bit_cast(h2, vv.x) * wg2;
                    O[4*h+1] += __builtin_bit_cast(h2, vv.y) * wg2;
                    O[4*h+2] += __builtin_bit_cast(h2, vv.z) * wg2;
                    O[4*h+3] += __builtin_bit_cast(h2, vv.w) * wg2;
                }
            }
            #pragma unroll
            for (int h = 0; h < 4; ++h) {            // normalize
                float rdh = __builtin_amdgcn_rcpf(den[h]);
                h2 rr = __builtin_bit_cast(h2, pkh(rdh, rdh));
                O[4*h+0] *= rr; O[4*h+1] *= rr; O[4*h+2] *= rr; O[4*h+3] *= rr;
            }
            #pragma unroll
            for (int g = 0; g < 4; ++g) {            // O -> KP own row (over K; reads done)
                uint4 w;
                w.x = __builtin_bit_cast(unsigned int, O[4*g+0]);
                w.y = __builtin_bit_cast(unsigned int, O[4*g+1]);
                w.z = __builtin_bit_cast(unsigned int, O[4*g+2]);
                w.w = __builtin_bit_cast(unsigned int, O[4*g+3]);
                *(uint4*)&S[KP + tid*16 + ((g ^ myk) << 2)] = w;
            }
        }

        // ---- O.Wo: A=KP(O) -> D=XN (over V; PV reads issued) ----
        {
            h8 bo0 = ldh(wsL + 1536 +  llo    *16 + boff);
            h8 bo1 = ldh(wsL + 1536 + (llo+16)*16 + boff);
            #pragma unroll
            for (int j = 0; j < 4; ++j) {
                int rowa = wid*64 + j*16 + llo;
                h8 a = ldh(&S[KP + rowa*16 + swg(rowa, lhi)]);
                f32x4 o0 = __builtin_amdgcn_mfma_f32_16x16x32_f16(a, bo0, zz, 0,0,0);
                f32x4 o1 = __builtin_amdgcn_mfma_f32_16x16x32_f16(a, bo1, zz, 0,0,0);
                int rowb = wid*64 + j*16 + lhi*4;
                #pragma unroll
                for (int rg = 0; rg < 4; ++rg) {
                    int row = rowb + rg;
                    S[XN + row*16 + swg(row, llo >> 2) + (llo & 3)] = pkh(o0[rg], o1[rg]);
                }
            }
        }
        #pragma unroll
        for (int g = 0; g < 4; ++g) {                // residual (own slot)
            uint4 v = *(const uint4*)&S[XN + tid*16 + ((g ^ myk) << 2)];
            X[4*g+0] += lo16(v.x); X[16+4*g+0] += hi16(v.x);
            X[4*g+1] += lo16(v.y); X[16+4*g+1] += hi16(v.y);
            X[4*g+2] += lo16(v.z); X[16+4*g+2] += hi16(v.z);
            X[4*g+3] += lo16(v.w); X[16+4*g+3] += hi16(v.w);
        }
        ln_write(X, &S[KP], tid);                    // Xn2 -> KP (over O; A reads issued)

        // ---- FFN: A=KP(Xn2), H->XN, FFN2 accumulates in regs ----
        f32x4 cf[4][2];
        #pragma unroll
        for (int j = 0; j < 4; ++j) { cf[j][0] = zz; cf[j][1] = zz; }
        #pragma unroll
        for (int q = 0; q < 4; ++q) {
            const unsigned int* wq4 = wsL + 2048 + q*1024;
            h8 b10 = ldh(wq4 +        llo    *16 + boff);
            h8 b11 = ldh(wq4 +       (llo+16)*16 + boff);
            h8 b20 = ldh(wq4 + 512 +  llo    *16 + boff);
            h8 b21 = ldh(wq4 + 512 + (llo+16)*16 + boff);
            #pragma unroll
            for (int j = 0; j < 4; ++j) {
                int rowa = wid*64 + j*16 + llo;
                h8 a = ldh(&S[KP + rowa*16 + swg(rowa, lhi)]);
                f32x4 h0 = __builtin_amdgcn_mfma_f32_16x16x32_f16(a, b10, zz, 0,0,0);
                f32x4 h1 = __builtin_amdgcn_mfma_f32_16x16x32_f16(a, b11, zz, 0,0,0);
                int rowb = wid*64 + j*16 + lhi*4;
                #pragma unroll
                for (int rg = 0; rg < 4; ++rg) {
                    int row = rowb + rg;
                    S[XN + row*16 + swg(row, llo >> 2) + (llo & 3)] =
                        pkh(gelu_f(h0[rg]), gelu_f(h1[rg]));
                }
            }
            #pragma unroll
            for (int j = 0; j < 4; ++j) {            // FFN2 (H rows in-wave)
                int rowa = wid*64 + j*16 + llo;
                h8 ah = ldh(&S[XN + rowa*16 + swg(rowa, lhi)]);
                cf[j][0] = __builtin_amdgcn_mfma_f32_16x16x32_f16(ah, b20, cf[j][0], 0,0,0);
                cf[j][1] = __builtin_amdgcn_mfma_f32_16x16x32_f16(ah, b21, cf[j][1], 0,0,0);
            }
        }
        #pragma unroll
        for (int j = 0; j < 4; ++j) {                // FFN2 out -> XN (over H)
            int rowb = wid*64 + j*16 + lhi*4;
            #pragma unroll
            for (int rg = 0; rg < 4; ++rg) {
                int row = rowb + rg;
                S[XN + row*16 + swg(row, llo >> 2) + (llo & 3)] = pkh(cf[j][0][rg], cf[j][1][rg]);
            }
        }
        #pragma unroll
        for (int g = 0; g < 4; ++g) {                // residual (own slot)
            uint4 v = *(const uint4*)&S[XN + tid*16 + ((g ^ myk) << 2)];
            X[4*g+0] += lo16(v.x); X[16+4*g+0] += hi16(v.x);
            X[4*g+1] += lo16(v.y); X[16+4*g+1] += hi16(v.y);
            X[4*g+2] += lo16(v.z); X[16+4*g+2] += hi16(v.z);
            X[4*g+3] += lo16(v.w); X[16+4*g+3] += hi16(v.w);
        }
    }

    // ---- final LN + weight-tied logits ----
    ln_write(X, &S[XN], tid);
    {
        h8 bt = ldh(ws + 12288 + llo*16 + boff);
        #pragma unroll
        for (int j = 0; j < 4; ++j) {
            int rowa = wid*64 + j*16 + llo;
            h8 a = ldh(&S[XN + rowa*16 + swg(rowa, lhi)]);
            f32x4 lg = __builtin_amdgcn_mfma_f32_16x16x32_f16(a, bt, zz, 0,0,0);
            int rowb = wid*64 + j*16 + lhi*4;
            #pragma unroll
            for (int rg = 0; rg < 4; ++rg) {
                int row = rowb + rg;
                S[KP + row*16 + swg(row, llo >> 2) + (llo & 3)] = __float_as_uint(lg[rg]);
            }
        }
    }
    __syncthreads();                                 // the only barrier
    {
        const long long obase = (long long)blockIdx.x * (ELB*SEQ*VOC);   // 3600
        const long long tot   = (long long)nelem * (SEQ*VOC);
        for (int i = tid; i < ELB*SEQ*VOC; i += THREADS) {
            if (obase + i < tot) {
                int rl   = i / VOC, col = i - rl*VOC;
                int w    = rl / 60, r6 = rl - w*60;
                int slot = w*64 + r6;
                out[obase + i] = __uint_as_float(
                    S[KP + slot*16 + (((col >> 2) ^ ((slot >> 1) & 3)) << 2) + (col & 3)]);
            }
        }
    }
}

extern "C" void kernel_launch(void* const* d_in, const int* in_sizes, int n_in,
                              void* d_out, int out_size, void* d_ws, size_t ws_size,
                              hipStream_t stream) {
    const int*   toks = (const int*)  d_in[0];
    const float* temb = (const float*)d_in[1];
    const float* pemb = (const float*)d_in[2];
    const float* wq   = (const float*)d_in[3];
    const float* wk   = (const float*)d_in[4];
    const float* wv   = (const float*)d_in[5];
    const float* wo   = (const float*)d_in[6];
    const float* w1   = (const float*)d_in[7];
    const float* w2   = (const float*)d_in[8];
    unsigned int* ws  = (unsigned int*)d_ws;         // 12544 u32 = 50 KB used
    float* out = (float*)d_out;
    const int nelem = in_sizes[0] / SEQ;             // 131072
    const int nblk  = (nelem + ELB - 1) / ELB;       // 3277

    prep<<<dim3(25), dim3(64), 0, stream>>>(temb, wq, wk, wv, wo, w1, w2, ws);
    tf_mfma<<<dim3(nblk), dim3(THREADS), 0, stream>>>(toks, temb, pemb, ws, out, nelem);
}

// Round 13
// 141.243 us; speedup vs baseline: 1.9704x; 1.0216x over previous
//
#include <hip/hip_runtime.h>

#define SEQ 6
#define THREADS 256              // 4 waves; 10 elements per wave (60 active lanes)
#define ELB 40                   // elements per block
#define NL 2
#define VOC 15

typedef __attribute__((ext_vector_type(8))) _Float16 h8;
typedef __attribute__((ext_vector_type(2))) _Float16 h2;
typedef __attribute__((ext_vector_type(4))) float    f32x4;

// LDS: 2 pools x 256 slots x 16 u32, XOR-swizzled 16B groups. 8192 u32 = 32 KB.
// Slot = tid (wave w owns slots 64w..64w+63). All intra-layer traffic is
// within-wave (in-order DS pipe) -> zero barriers until logits staging.
#define XN 0          // Xn -> Q -> V -> OWo -> H -> FFN2
#define KP 4096       // K -> O -> Xn2 -> logits f32
#define SMEM_U32 8192

// ws layout (u32): per layer L at L*6144: Wq 0, Wk 512, Wv 1024, Wo 1536,
// quarter q: 2048+q*1024 (W1q at +0, W2q at +512). TE at 12288 (256).

__device__ __forceinline__ unsigned int pkh(float a, float b) {
    auto h = __builtin_amdgcn_cvt_pkrtz(a, b);
    return __builtin_bit_cast(unsigned int, h);
}
__device__ __forceinline__ float lo16(unsigned int u) {
    h2 h = __builtin_bit_cast(h2, u); return (float)h.x;
}
__device__ __forceinline__ float hi16(unsigned int u) {
    h2 h = __builtin_bit_cast(h2, u); return (float)h.y;
}
__device__ __forceinline__ h8 ldh(const unsigned int* p) {
    uint4 u = *(const uint4*)p;
    return __builtin_bit_cast(h8, u);
}
#if __has_builtin(__builtin_amdgcn_fdot2)
__device__ __forceinline__ float dot2acc(unsigned int a, unsigned int b, float c) {
    return __builtin_amdgcn_fdot2(__builtin_bit_cast(h2, a), __builtin_bit_cast(h2, b), c, false);
}
#else
__device__ __forceinline__ float dot2acc(unsigned int a, unsigned int b, float c) {
    return fmaf(hi16(a), hi16(b), fmaf(lo16(a), lo16(b), c));
}
#endif
#define H2C(v) ((h2){(_Float16)(v), (_Float16)(v)})
// GELU on a PAIR, evaluated in packed f16 (v_pk_* ops, 2 lanes' worth per inst).
// Odd-poly fit of erf(x/sqrt2) on |x|<=3 (|err|<=3e-3 f32; f16 Horner adds <=4e-3).
// Returns the packed-f16 result ready for LDS store (no separate pkh needed).
__device__ __forceinline__ unsigned int gelu2(float a, float b) {
    h2 xp = __builtin_bit_cast(h2, pkh(a, b));
#if __has_builtin(__builtin_elementwise_max) && __has_builtin(__builtin_elementwise_min)
    h2 xc = __builtin_elementwise_min(__builtin_elementwise_max(xp, H2C(-3.0f)), H2C(3.0f));
#else
    h2 xc = __builtin_bit_cast(h2, pkh(fminf(fmaxf(a, -3.0f), 3.0f),
                                       fminf(fmaxf(b, -3.0f), 3.0f)));
#endif
    h2 u = xc * xc;
    h2 p = H2C(4.80757e-5f);
    p = p * u + H2C(-1.40632e-3f);
    p = p * u + H2C(1.75795e-2f);
    p = p * u + H2C(-1.30947e-1f);
    p = p * u + H2C(7.9714e-1f);
    h2 hx = xp * H2C(0.5f);
    h2 r  = (hx * xc) * p + hx;                  // 0.5x(1 + xc*P(u))
    return __builtin_bit_cast(unsigned int, r);
}
__device__ __forceinline__ int permc(int p) {        // head-local sigma pairs
    int h = (p & 15) >> 2, j = p & 3, hi = p >> 4;
    return 8*h + 2*j + hi;
}
__device__ __forceinline__ int swg(int row, int g) { // swizzled 16B-group offset
    return ((g ^ ((row >> 1) & 3)) << 2);
}
__device__ __forceinline__ void ln_write(const float* X, unsigned int* base, int row) {
    float mu = 0.f;
    #pragma unroll
    for (int c = 0; c < 32; ++c) mu += X[c];
    mu *= 0.03125f;
    float var = 0.f;
    #pragma unroll
    for (int c = 0; c < 32; ++c) { float d = X[c] - mu; var += d * d; }
    var *= 0.03125f;
    float rs = rsqrtf(var + 1e-5f), b = -mu * rs;
    unsigned int* rp = base + row * 16;
    const int k = (row >> 1) & 3;
    #pragma unroll
    for (int g = 0; g < 4; ++g) {
        uint4 w;
        w.x = pkh(fmaf(X[4*g+0], rs, b), fmaf(X[16+4*g+0], rs, b));
        w.y = pkh(fmaf(X[4*g+1], rs, b), fmaf(X[16+4*g+1], rs, b));
        w.z = pkh(fmaf(X[4*g+2], rs, b), fmaf(X[16+4*g+2], rs, b));
        w.w = pkh(fmaf(X[4*g+3], rs, b), fmaf(X[16+4*g+3], rs, b));
        *(uint4*)&rp[(g ^ k) << 2] = w;
    }
}

// ---- prep: pre-pack all weights (f16, transposed, head-permuted) into ws ----
__global__ __launch_bounds__(64) void prep(
    const float* __restrict__ temb, const float* __restrict__ wq,
    const float* __restrict__ wk, const float* __restrict__ wv,
    const float* __restrict__ wo, const float* __restrict__ w1,
    const float* __restrict__ w2, unsigned int* __restrict__ ws)
{
    const int part = blockIdx.x;          // 0..24
    const int t = threadIdx.x;
    if (part == 24) {                     // TE tile
        for (int i = t; i < 256; i += 64) {
            int c = i >> 4, w = i & 15;
            ws[12288 + i] = (c < VOC) ? pkh(temb[c*32 + w], temb[c*32 + w + 16]) : 0u;
        }
        return;
    }
    const int L = part / 12, m = part % 12;
    unsigned int* o = ws + L * 6144;
    for (int i = t; i < 512; i += 64) {
        int c = i >> 4, w = i & 15;
        if (m < 3) {
            const float* M = (m == 0 ? wq : (m == 1 ? wk : wv)) + L*1024;
            int pc = permc(c);
            o[m*512 + i] = pkh(M[w*32 + pc], M[(w+16)*32 + pc]);
        } else if (m == 3) {
            const float* M = wo + L*1024;
            o[1536 + i] = pkh(M[permc(w)*32 + c], M[permc(w+16)*32 + c]);
        } else if (m < 8) {
            int q = m - 4;
            const float* M = w1 + L*4096;
            o[2048 + q*1024 + i] = pkh(M[w*128 + 32*q + c], M[(w+16)*128 + 32*q + c]);
        } else {
            int q = m - 8;
            const float* M = w2 + L*4096;
            o[2048 + q*1024 + 512 + i] = pkh(M[(32*q+w)*32 + c], M[(32*q+16+w)*32 + c]);
        }
    }
}

// w=3: reg budget ~170/wave (unified VGPR+AGPR; total alloc sits in (128,170] ->
// HW residency 3 waves/SIMD). w=4 (128) forces 64-arch clamp + spill (R7).
__global__ __launch_bounds__(THREADS, 3)
void tf_mfma(const int* __restrict__ toks, const float* __restrict__ temb,
             const float* __restrict__ pemb, const unsigned int* __restrict__ ws,
             float* __restrict__ out, int nelem)
{
    __shared__ unsigned int S[SMEM_U32];
    const int tid  = threadIdx.x;
    const int lane = tid & 63;
    const int wid  = tid >> 6;
    const int llo  = lane & 15, lhi = lane >> 4;
    const int boff = 4 * lhi;
    int le = lane / 6;
    int s  = lane - le * 6;
    if (le > 9) { le = 9; s = 5; }                   // 4 dup lanes/wave (in-bounds)
    const int rb   = wid*64 + le*6;                  // element's slot base (in-wave)
    const int myk  = (tid >> 1) & 3;
    const int elem = blockIdx.x * ELB + wid*10 + le;
    const f32x4 zz = {0.f, 0.f, 0.f, 0.f};

    float X[32];
    {
        const int ti  = (elem < nelem) ? (elem*SEQ + s) : 0;
        const int tok = toks[ti];
        #pragma unroll
        for (int g = 0; g < 8; ++g) {
            float4 a = *(const float4*)&temb[tok*32 + 4*g];
            float4 b = *(const float4*)&pemb[s*32 + 4*g];
            X[4*g+0] = a.x + b.x; X[4*g+1] = a.y + b.y;
            X[4*g+2] = a.z + b.z; X[4*g+3] = a.w + b.w;
        }
    }

    #pragma unroll 1
    for (int L = 0; L < NL; ++L) {
        const unsigned int* wsL = ws + L * 6144;

        ln_write(X, &S[XN], tid);                    // Xn (own slot)

        // ---- QKV (weights direct from global; all LDS traffic in-wave) ----
        uint4 q4[4];
        {
            h8 bq0 = ldh(wsL +          llo    *16 + boff);
            h8 bq1 = ldh(wsL +         (llo+16)*16 + boff);
            h8 bk0 = ldh(wsL +  512 +   llo    *16 + boff);
            h8 bk1 = ldh(wsL +  512 +  (llo+16)*16 + boff);
            h8 bv0 = ldh(wsL + 1024 +   llo    *16 + boff);
            h8 bv1 = ldh(wsL + 1024 +  (llo+16)*16 + boff);
            h8 aa[4];
            #pragma unroll
            for (int j = 0; j < 4; ++j) {
                int rowa = wid*64 + j*16 + llo;
                aa[j] = ldh(&S[XN + rowa*16 + swg(rowa, lhi)]);
            }
            #pragma unroll
            for (int j = 0; j < 4; ++j) {            // K -> KP
                f32x4 k0 = __builtin_amdgcn_mfma_f32_16x16x32_f16(aa[j], bk0, zz, 0,0,0);
                f32x4 k1 = __builtin_amdgcn_mfma_f32_16x16x32_f16(aa[j], bk1, zz, 0,0,0);
                int rowb = wid*64 + j*16 + lhi*4;
                #pragma unroll
                for (int rg = 0; rg < 4; ++rg) {
                    int row = rowb + rg;
                    S[KP + row*16 + swg(row, llo >> 2) + (llo & 3)] = pkh(k0[rg], k1[rg]);
                }
            }
            #pragma unroll
            for (int j = 0; j < 4; ++j) {            // Q -> XN (over Xn; aa read done)
                f32x4 qa = __builtin_amdgcn_mfma_f32_16x16x32_f16(aa[j], bq0, zz, 0,0,0);
                f32x4 qb = __builtin_amdgcn_mfma_f32_16x16x32_f16(aa[j], bq1, zz, 0,0,0);
                int rowb = wid*64 + j*16 + lhi*4;
                #pragma unroll
                for (int rg = 0; rg < 4; ++rg) {
                    int row = rowb + rg;
                    S[XN + row*16 + swg(row, llo >> 2) + (llo & 3)] = pkh(qa[rg], qb[rg]);
                }
            }
            #pragma unroll
            for (int h = 0; h < 4; ++h)              // own-row Q (in-wave RAW, in-order DS)
                q4[h] = *(const uint4*)&S[XN + tid*16 + ((h ^ myk) << 2)];
            #pragma unroll
            for (int j = 0; j < 4; ++j) {            // V -> XN (over Q; q4 reads issued)
                f32x4 v0 = __builtin_amdgcn_mfma_f32_16x16x32_f16(aa[j], bv0, zz, 0,0,0);
                f32x4 v1 = __builtin_amdgcn_mfma_f32_16x16x32_f16(aa[j], bv1, zz, 0,0,0);
                int rowb = wid*64 + j*16 + lhi*4;
                #pragma unroll
                for (int rg = 0; rg < 4; ++rg) {
                    int row = rowb + rg;
                    S[XN + row*16 + swg(row, llo >> 2) + (llo & 3)] = pkh(v0[rg], v1[rg]);
                }
            }
        }

        // ---- attention: ONLINE scores+PV in one pass ----
        // exp2 with folded scale: 0.35355339*log2(e) = 0.51006975. exp2(-1e30)=0 masks.
        {
            float den[4] = {0.f, 0.f, 0.f, 0.f};
            h2 O[16];
            #pragma unroll
            for (int w = 0; w < 16; ++w) O[w] = __builtin_bit_cast(h2, 0u);
            #pragma unroll
            for (int t = 0; t < SEQ; ++t) {
                int krow = rb + t;
                const unsigned int* kr = &S[KP + krow*16];
                const unsigned int* vr = &S[XN + krow*16];
                int kk4 = (krow >> 1) & 3;
                float msk = (t <= s) ? 0.f : -1e30f;
                #pragma unroll
                for (int h = 0; h < 4; ++h) {
                    uint4 kk = *(const uint4*)&kr[(h ^ kk4) << 2];
                    float d = dot2acc(q4[h].x, kk.x, 0.f);
                    d = dot2acc(q4[h].y, kk.y, d);
                    d = dot2acc(q4[h].z, kk.z, d);
                    d = dot2acc(q4[h].w, kk.w, d);
                    float e = exp2f(fmaf(d, 0.51006975f, msk));
                    den[h] += e;
                    h2 wg2 = __builtin_bit_cast(h2, pkh(e, e));
                    uint4 vv = *(const uint4*)&vr[(h ^ kk4) << 2];
                    O[4*h+0] += __builtin_bit_cast(h2, vv.x) * wg2;
                    O[4*h+1] += __builtin_bit_cast(h2, vv.y) * wg2;
                    O[4*h+2] += __builtin_bit_cast(h2, vv.z) * wg2;
                    O[4*h+3] += __builtin_bit_cast(h2, vv.w) * wg2;
                }
            }
            #pragma unroll
            for (int h = 0; h < 4; ++h) {            // normalize
                float rdh = __builtin_amdgcn_rcpf(den[h]);
                h2 rr = __builtin_bit_cast(h2, pkh(rdh, rdh));
                O[4*h+0] *= rr; O[4*h+1] *= rr; O[4*h+2] *= rr; O[4*h+3] *= rr;
            }
            #pragma unroll
            for (int g = 0; g < 4; ++g) {            // O -> KP own row (over K; reads done)
                uint4 w;
                w.x = __builtin_bit_cast(unsigned int, O[4*g+0]);
                w.y = __builtin_bit_cast(unsigned int, O[4*g+1]);
                w.z = __builtin_bit_cast(unsigned int, O[4*g+2]);
                w.w = __builtin_bit_cast(unsigned int, O[4*g+3]);
                *(uint4*)&S[KP + tid*16 + ((g ^ myk) << 2)] = w;
            }
        }

        // ---- O.Wo: A=KP(O) -> D=XN (over V; PV reads issued) ----
        {
            h8 bo0 = ldh(wsL + 1536 +  llo    *16 + boff);
            h8 bo1 = ldh(wsL + 1536 + (llo+16)*16 + boff);
            #pragma unroll
            for (int j = 0; j < 4; ++j) {
                int rowa = wid*64 + j*16 + llo;
                h8 a = ldh(&S[KP + rowa*16 + swg(rowa, lhi)]);
                f32x4 o0 = __builtin_amdgcn_mfma_f32_16x16x32_f16(a, bo0, zz, 0,0,0);
                f32x4 o1 = __builtin_amdgcn_mfma_f32_16x16x32_f16(a, bo1, zz, 0,0,0);
                int rowb = wid*64 + j*16 + lhi*4;
                #pragma unroll
                for (int rg = 0; rg < 4; ++rg) {
                    int row = rowb + rg;
                    S[XN + row*16 + swg(row, llo >> 2) + (llo & 3)] = pkh(o0[rg], o1[rg]);
                }
            }
        }
        #pragma unroll
        for (int g = 0; g < 4; ++g) {                // residual (own slot)
            uint4 v = *(const uint4*)&S[XN + tid*16 + ((g ^ myk) << 2)];
            X[4*g+0] += lo16(v.x); X[16+4*g+0] += hi16(v.x);
            X[4*g+1] += lo16(v.y); X[16+4*g+1] += hi16(v.y);
            X[4*g+2] += lo16(v.z); X[16+4*g+2] += hi16(v.z);
            X[4*g+3] += lo16(v.w); X[16+4*g+3] += hi16(v.w);
        }
        ln_write(X, &S[KP], tid);                    // Xn2 -> KP (over O; A reads issued)

        // ---- FFN: A=KP(Xn2), H->XN (packed-f16 GELU), FFN2 accumulates in regs ----
        f32x4 cf[4][2];
        #pragma unroll
        for (int j = 0; j < 4; ++j) { cf[j][0] = zz; cf[j][1] = zz; }
        #pragma unroll
        for (int q = 0; q < 4; ++q) {
            const unsigned int* wq4 = wsL + 2048 + q*1024;
            h8 b10 = ldh(wq4 +        llo    *16 + boff);
            h8 b11 = ldh(wq4 +       (llo+16)*16 + boff);
            h8 b20 = ldh(wq4 + 512 +  llo    *16 + boff);
            h8 b21 = ldh(wq4 + 512 + (llo+16)*16 + boff);
            #pragma unroll
            for (int j = 0; j < 4; ++j) {
                int rowa = wid*64 + j*16 + llo;
                h8 a = ldh(&S[KP + rowa*16 + swg(rowa, lhi)]);
                f32x4 h0 = __builtin_amdgcn_mfma_f32_16x16x32_f16(a, b10, zz, 0,0,0);
                f32x4 h1 = __builtin_amdgcn_mfma_f32_16x16x32_f16(a, b11, zz, 0,0,0);
                int rowb = wid*64 + j*16 + lhi*4;
                #pragma unroll
                for (int rg = 0; rg < 4; ++rg) {
                    int row = rowb + rg;
                    S[XN + row*16 + swg(row, llo >> 2) + (llo & 3)] = gelu2(h0[rg], h1[rg]);
                }
            }
            #pragma unroll
            for (int j = 0; j < 4; ++j) {            // FFN2 (H rows in-wave)
                int rowa = wid*64 + j*16 + llo;
                h8 ah = ldh(&S[XN + rowa*16 + swg(rowa, lhi)]);
                cf[j][0] = __builtin_amdgcn_mfma_f32_16x16x32_f16(ah, b20, cf[j][0], 0,0,0);
                cf[j][1] = __builtin_amdgcn_mfma_f32_16x16x32_f16(ah, b21, cf[j][1], 0,0,0);
            }
        }
        #pragma unroll
        for (int j = 0; j < 4; ++j) {                // FFN2 out -> XN (over H)
            int rowb = wid*64 + j*16 + lhi*4;
            #pragma unroll
            for (int rg = 0; rg < 4; ++rg) {
                int row = rowb + rg;
                S[XN + row*16 + swg(row, llo >> 2) + (llo & 3)] = pkh(cf[j][0][rg], cf[j][1][rg]);
            }
        }
        #pragma unroll
        for (int g = 0; g < 4; ++g) {                // residual (own slot)
            uint4 v = *(const uint4*)&S[XN + tid*16 + ((g ^ myk) << 2)];
            X[4*g+0] += lo16(v.x); X[16+4*g+0] += hi16(v.x);
            X[4*g+1] += lo16(v.y); X[16+4*g+1] += hi16(v.y);
            X[4*g+2] += lo16(v.z); X[16+4*g+2] += hi16(v.z);
            X[4*g+3] += lo16(v.w); X[16+4*g+3] += hi16(v.w);
        }
    }

    // ---- final LN + weight-tied logits ----
    ln_write(X, &S[XN], tid);
    {
        h8 bt = ldh(ws + 12288 + llo*16 + boff);
        #pragma unroll
        for (int j = 0; j < 4; ++j) {
            int rowa = wid*64 + j*16 + llo;
            h8 a = ldh(&S[XN + rowa*16 + swg(rowa, lhi)]);
            f32x4 lg = __builtin_amdgcn_mfma_f32_16x16x32_f16(a, bt, zz, 0,0,0);
            int rowb = wid*64 + j*16 + lhi*4;
            #pragma unroll
            for (int rg = 0; rg < 4; ++rg) {
                int row = rowb + rg;
                S[KP + row*16 + swg(row, llo >> 2) + (llo & 3)] = __float_as_uint(lg[rg]);
            }
        }
    }
    __syncthreads();                                 // the only barrier
    {
        const long long obase = (long long)blockIdx.x * (ELB*SEQ*VOC);   // 3600
        const long long tot   = (long long)nelem * (SEQ*VOC);
        for (int i = tid; i < ELB*SEQ*VOC; i += THREADS) {
            if (obase + i < tot) {
                int rl   = i / VOC, col = i - rl*VOC;
                int w    = rl / 60, r6 = rl - w*60;
                int slot = w*64 + r6;
                out[obase + i] = __uint_as_float(
                    S[KP + slot*16 + (((col >> 2) ^ ((slot >> 1) & 3)) << 2) + (col & 3)]);
            }
        }
    }
}

extern "C" void kernel_launch(void* const* d_in, const int* in_sizes, int n_in,
                              void* d_out, int out_size, void* d_ws, size_t ws_size,
                              hipStream_t stream) {
    const int*   toks = (const int*)  d_in[0];
    const float* temb = (const float*)d_in[1];
    const float* pemb = (const float*)d_in[2];
    const float* wq   = (const float*)d_in[3];
    const float* wk   = (const float*)d_in[4];
    const float* wv   = (const float*)d_in[5];
    const float* wo   = (const float*)d_in[6];
    const float* w1   = (const float*)d_in[7];
    const float* w2   = (const float*)d_in[8];
    unsigned int* ws  = (unsigned int*)d_ws;         // 12544 u32 = 50 KB used
    float* out = (float*)d_out;
    const int nelem = in_sizes[0] / SEQ;             // 131072
    const int nblk  = (nelem + ELB - 1) / ELB;       // 3277

    prep<<<dim3(25), dim3(64), 0, stream>>>(temb, wq, wk, wv, wo, w1, w2, ws);
    tf_mfma<<<dim3(nblk), dim3(THREADS), 0, stream>>>(toks, temb, pemb, ws, out, nelem);
}